// Round 12
// baseline (268.141 us; speedup 1.0000x reference)
//
#include <hip/hip_runtime.h>
#include <math.h>

#define N_NODES 50000
#define N_EDGES 400000
#define E_TOT   (N_EDGES + N_NODES)
#define NG      64
#define NEG_SLOPE 0.2f

typedef __attribute__((ext_vector_type(8))) short bf16x8;
typedef __attribute__((ext_vector_type(4))) float f32x4;

// ---------------- helpers ----------------
__device__ __forceinline__ float lrelu(float x){ return x > 0.f ? x : NEG_SLOPE * x; }
__device__ __forceinline__ ushort f2bf(float f){
  union { float f; unsigned u; } v; v.f = f;
  unsigned r = v.u + 0x7FFFu + ((v.u >> 16) & 1u);  // RNE
  return (ushort)(r >> 16);
}
__device__ __forceinline__ float bf2f(ushort u){
  return __uint_as_float(((unsigned)u) << 16);
}

// ---------------- setup: prep weights + graph bounds + edge count, ONE kernel ----------------
#define SETUP_PREP   (2048 + 2 * 32768)
#define SETUP_BOUNDS (SETUP_PREP + N_NODES + 1)
#define SETUP_TOTAL  (SETUP_BOUNDS + E_TOT)

__global__ void setup_kernel(const float* __restrict__ W1, const float* __restrict__ as1,
                             const float* __restrict__ ad1, const float* __restrict__ W2,
                             const float* __restrict__ as2, const float* __restrict__ ad2,
                             const int* __restrict__ batch, const int* __restrict__ ei,
                             float* __restrict__ wa1, float* __restrict__ wa2,
                             ushort* __restrict__ w1pT, ushort* __restrict__ w2pT,
                             int* __restrict__ gstart, int* __restrict__ counts){
  int idx = blockIdx.x * blockDim.x + threadIdx.x;
  if (idx < 2048){
    const float* W = (idx < 1024) ? W1 : W2;
    const float* asr = (idx < 1024) ? as1 : as2;
    const float* adr = (idx < 1024) ? ad1 : ad2;
    float* wa = (idx < 1024) ? wa1 : wa2;
    int i = idx & 1023;
    int k = i >> 4, c = i & 15;
    int h = c & 7;
    const float* a = (c < 8) ? asr : adr;
    float s = 0.f;
#pragma unroll
    for (int d = 0; d < 64; ++d) s = fmaf(W[k * 512 + h * 64 + d], a[h * 64 + d], s);
    wa[i] = s;
  } else if (idx < SETUP_PREP){
    int i = idx - 2048;
    const float* W = (i < 32768) ? W1 : W2;
    ushort* wpT = (i < 32768) ? w1pT : w2pT;
    i &= 32767;
    // k-order = d*8 + h (matches wagg's packed store)
    int j = i >> 9, k = i & 511;
    int d = k >> 3, h = k & 7;
    wpT[i] = f2bf(W[d * 512 + h * 64 + j] * 0.125f);
  } else if (idx < SETUP_BOUNDS){
    int n = idx - SETUP_PREP;
    int g = (n < N_NODES) ? batch[n] : NG;
    if (n == 0){
      for (int gg = 0; gg <= g; ++gg) gstart[gg] = 0;
    } else {
      int gp = batch[n - 1];
      for (int gg = gp + 1; gg <= g; ++gg) gstart[gg] = n;
    }
  } else if (idx < SETUP_TOTAL){
    int e = idx - SETUP_BOUNDS;
    int dst = (e < N_EDGES) ? ei[N_EDGES + e] : (e - N_EDGES);
    atomicAdd(&counts[dst], 1);
  }
}

// ---------- two-level exclusive scan of counts[N_NODES] -> row_off ----------
#define SCAN_B 1024
#define SCAN_NB ((N_NODES + SCAN_B - 1) / SCAN_B)   // 49

__global__ __launch_bounds__(SCAN_B) void scan1_kernel(const int* __restrict__ counts,
                                                       int* __restrict__ row_off,
                                                       int* __restrict__ blocksum){
  __shared__ int sh[SCAN_B];
  int i = blockIdx.x * SCAN_B + threadIdx.x;
  int v = (i < N_NODES) ? counts[i] : 0;
  sh[threadIdx.x] = v;
  __syncthreads();
#pragma unroll
  for (int off = 1; off < SCAN_B; off <<= 1){
    int add = (threadIdx.x >= (unsigned)off) ? sh[threadIdx.x - off] : 0;
    __syncthreads();
    sh[threadIdx.x] += add;
    __syncthreads();
  }
  if (i < N_NODES) row_off[i] = sh[threadIdx.x] - v;
  if (threadIdx.x == SCAN_B - 1) blocksum[blockIdx.x] = sh[SCAN_B - 1];
}

__global__ void scan2_kernel(int* __restrict__ blocksum, int* __restrict__ blockoff){
  __shared__ int sh[64];
  int t = threadIdx.x;
  int v = (t < SCAN_NB) ? blocksum[t] : 0;
  sh[t] = v;
  __syncthreads();
#pragma unroll
  for (int off = 1; off < 64; off <<= 1){
    int add = (t >= off) ? sh[t - off] : 0;
    __syncthreads();
    sh[t] += add;
    __syncthreads();
  }
  if (t < SCAN_NB) blockoff[t] = sh[t] - v;
  if (t == 63) blockoff[SCAN_NB] = sh[63];
}

__global__ void scan3_kernel(int* __restrict__ row_off, const int* __restrict__ blockoff){
  int i = blockIdx.x * blockDim.x + threadIdx.x;
  if (i < N_NODES) row_off[i] += blockoff[i >> 10];
  if (i == 0) row_off[N_NODES] = blockoff[SCAN_NB];
}

__global__ void scatter_kernel(const int* __restrict__ ei, const int* __restrict__ row_off,
                               int* __restrict__ cursor, int* __restrict__ csr_src){
  int e = blockIdx.x * blockDim.x + threadIdx.x;
  if (e >= E_TOT) return;
  int src, dst;
  if (e < N_EDGES){ src = ei[e]; dst = ei[N_EDGES + e]; }
  else            { src = dst = e - N_EDGES; }
  int pos = row_off[dst] + atomicAdd(&cursor[dst], 1);
  csr_src[pos] = src;
}

// ---------------- layer1 al from f32 x; also emits x as bf16 ----------------
__global__ void al1_kernel(const float* __restrict__ xin, const float* __restrict__ wa,
                           float* __restrict__ al, ushort* __restrict__ xbf){
  __shared__ float w[64 * 16];
  for (int i = threadIdx.x; i < 1024; i += blockDim.x) w[i] = wa[i];
  __syncthreads();
  int idx = blockIdx.x * blockDim.x + threadIdx.x;
  if (idx >= N_NODES * 16) return;
  int n = idx >> 4, c = idx & 15;
  const float* xr = xin + (size_t)n * 64;
  float s = 0.f;
#pragma unroll
  for (int k4 = 0; k4 < 16; ++k4){
    float4 v = *(const float4*)(xr + k4 * 4);
    s = fmaf(v.x, w[(k4 * 4 + 0) * 16 + c], s);
    s = fmaf(v.y, w[(k4 * 4 + 1) * 16 + c], s);
    s = fmaf(v.z, w[(k4 * 4 + 2) * 16 + c], s);
    s = fmaf(v.w, w[(k4 * 4 + 3) * 16 + c], s);
  }
  float4 mine = *(const float4*)(xr + c * 4);
  ushort ob[4] = {f2bf(mine.x), f2bf(mine.y), f2bf(mine.z), f2bf(mine.w)};
  *(ushort4*)(xbf + (size_t)n * 64 + c * 4) = *(const ushort4*)ob;
  al[idx] = s;
}

// ---------------- FUSED softmax weights + aggregation (v5) ----------------
// Barrier-free (wave-private LDS) + 8-edge x prefetch issued BEFORE softmax
// (clamped index, zero-padded weights -> guard-free consume). Weights staged
// UNNORMALIZED straight from the exp loop; acc scaled by 1/sum in epilogue.
__global__ __launch_bounds__(256) void wagg_kernel(const ushort* __restrict__ xb,
                                                   const float* __restrict__ al,
                                                   const int* __restrict__ row_off,
                                                   const int* __restrict__ csr_src,
                                                   ushort* __restrict__ aggx){
  __shared__ float ws[4][64][8];   // 8 KB, wave-private slices (unnormalized w)
  __shared__ float sinv[4][8];
  const int wave = threadIdx.x >> 6, lane = threadIdx.x & 63;
  const int n = blockIdx.x * 4 + wave;
  const int s0 = row_off[n], s1 = row_off[n + 1];
  const int deg = s1 - s0;   // >= 1 (self-loop)

  const int eo = lane >> 3, h = lane & 7;
  const float ald = al[n * 16 + 8 + h];

  // one load covers this node's first 64 src indices
  int idxv = (s0 + lane < s1) ? csr_src[s0 + lane] : 0;

  const bool fast = (deg <= 64);

  // issue first-8-edge x gathers NOW; they complete under the softmax phase.
  float xpre[8];
  if (fast){
#pragma unroll
    for (int i = 0; i < 8; ++i){
      int s = __shfl(idxv, min(i, deg - 1), 64);
      xpre[i] = bf2f(xb[(size_t)s * 64 + lane]);
    }
  }

  float sum = 0.f;
  if (fast){
    // exp + stage unnormalized weight immediately (0 beyond deg)
#pragma unroll
    for (int i = 0; i < 8; ++i){
      int ee = eo + i * 8;
      int s = __shfl(idxv, ee, 64);
      float v = 0.f;
      if (ee < deg) v = __expf(lrelu(al[s * 16 + h] + ald));
      ws[wave][ee][h] = v;
      sum += v;
    }
  } else {
    for (int e = s0 + eo; e < s1; e += 8){
      int s = csr_src[e];
      sum += __expf(lrelu(al[s * 16 + h] + ald));
    }
  }
#pragma unroll
  for (int off = 8; off < 64; off <<= 1) sum += __shfl_xor(sum, off, 64);
  if (eo == 0) sinv[wave][h] = 1.f / (sum + 1e-16f);

  float acc[8];
#pragma unroll
  for (int i = 0; i < 8; ++i) acc[i] = 0.f;

  const int nchunk = (deg + 63) >> 6;   // per-wave: no cross-wave coupling
  for (int c = 0; c < nchunk; ++c){
    const int base = s0 + c * 64;
    if (!fast){
      // generic staging for this chunk (unnormalized)
#pragma unroll
      for (int i = 0; i < 8; ++i){
        int e = base + eo + i * 8;
        if (e < s1){
          int s = csr_src[e];
          ws[wave][e - base][h] = __expf(lrelu(al[s * 16 + h] + ald));
        }
      }
    }
    __builtin_amdgcn_wave_barrier();   // no reorder of reads above writes
    const int cend = min(base + 64, s1);
    int e = base;
    if (fast && c == 0){
      // consume the prefetched 8 edges (ws zero-padded -> no guards)
#pragma unroll
      for (int i = 0; i < 8; ++i){
        float4 w0 = *(const float4*)&ws[wave][i][0];
        float4 w1 = *(const float4*)&ws[wave][i][4];
        float xa = xpre[i];
        acc[0] = fmaf(w0.x, xa, acc[0]); acc[1] = fmaf(w0.y, xa, acc[1]);
        acc[2] = fmaf(w0.z, xa, acc[2]); acc[3] = fmaf(w0.w, xa, acc[3]);
        acc[4] = fmaf(w1.x, xa, acc[4]); acc[5] = fmaf(w1.y, xa, acc[5]);
        acc[6] = fmaf(w1.z, xa, acc[6]); acc[7] = fmaf(w1.w, xa, acc[7]);
      }
      e = base + 8;
      if (e > cend) e = cend;
    }
    for (; e + 4 <= cend; e += 4){
      int r0 = e - base;
      int sa, sb, sc, sd;
      if (fast){
        sa = __shfl(idxv, e - s0, 64);
        sb = __shfl(idxv, e - s0 + 1, 64);
        sc = __shfl(idxv, e - s0 + 2, 64);
        sd = __shfl(idxv, e - s0 + 3, 64);
      } else {
        sa = csr_src[e]; sb = csr_src[e + 1]; sc = csr_src[e + 2]; sd = csr_src[e + 3];
      }
      float xa = bf2f(xb[(size_t)sa * 64 + lane]);
      float xc = bf2f(xb[(size_t)sb * 64 + lane]);
      float xe = bf2f(xb[(size_t)sc * 64 + lane]);
      float xg = bf2f(xb[(size_t)sd * 64 + lane]);
      float4 wa0 = *(const float4*)&ws[wave][r0][0];
      float4 wa1 = *(const float4*)&ws[wave][r0][4];
      float4 wb0 = *(const float4*)&ws[wave][r0 + 1][0];
      float4 wb1 = *(const float4*)&ws[wave][r0 + 1][4];
      float4 wc0 = *(const float4*)&ws[wave][r0 + 2][0];
      float4 wc1 = *(const float4*)&ws[wave][r0 + 2][4];
      float4 wd0 = *(const float4*)&ws[wave][r0 + 3][0];
      float4 wd1 = *(const float4*)&ws[wave][r0 + 3][4];
      acc[0] = fmaf(wa0.x, xa, acc[0]); acc[1] = fmaf(wa0.y, xa, acc[1]);
      acc[2] = fmaf(wa0.z, xa, acc[2]); acc[3] = fmaf(wa0.w, xa, acc[3]);
      acc[4] = fmaf(wa1.x, xa, acc[4]); acc[5] = fmaf(wa1.y, xa, acc[5]);
      acc[6] = fmaf(wa1.z, xa, acc[6]); acc[7] = fmaf(wa1.w, xa, acc[7]);
      acc[0] = fmaf(wb0.x, xc, acc[0]); acc[1] = fmaf(wb0.y, xc, acc[1]);
      acc[2] = fmaf(wb0.z, xc, acc[2]); acc[3] = fmaf(wb0.w, xc, acc[3]);
      acc[4] = fmaf(wb1.x, xc, acc[4]); acc[5] = fmaf(wb1.y, xc, acc[5]);
      acc[6] = fmaf(wb1.z, xc, acc[6]); acc[7] = fmaf(wb1.w, xc, acc[7]);
      acc[0] = fmaf(wc0.x, xe, acc[0]); acc[1] = fmaf(wc0.y, xe, acc[1]);
      acc[2] = fmaf(wc0.z, xe, acc[2]); acc[3] = fmaf(wc0.w, xe, acc[3]);
      acc[4] = fmaf(wc1.x, xe, acc[4]); acc[5] = fmaf(wc1.y, xe, acc[5]);
      acc[6] = fmaf(wc1.z, xe, acc[6]); acc[7] = fmaf(wc1.w, xe, acc[7]);
      acc[0] = fmaf(wd0.x, xg, acc[0]); acc[1] = fmaf(wd0.y, xg, acc[1]);
      acc[2] = fmaf(wd0.z, xg, acc[2]); acc[3] = fmaf(wd0.w, xg, acc[3]);
      acc[4] = fmaf(wd1.x, xg, acc[4]); acc[5] = fmaf(wd1.y, xg, acc[5]);
      acc[6] = fmaf(wd1.z, xg, acc[6]); acc[7] = fmaf(wd1.w, xg, acc[7]);
    }
    for (; e < cend; ++e){
      int r0 = e - base;
      int sa = fast ? __shfl(idxv, e - s0, 64) : csr_src[e];
      float xa = bf2f(xb[(size_t)sa * 64 + lane]);
      float4 wa0 = *(const float4*)&ws[wave][r0][0];
      float4 wa1 = *(const float4*)&ws[wave][r0][4];
      acc[0] = fmaf(wa0.x, xa, acc[0]); acc[1] = fmaf(wa0.y, xa, acc[1]);
      acc[2] = fmaf(wa0.z, xa, acc[2]); acc[3] = fmaf(wa0.w, xa, acc[3]);
      acc[4] = fmaf(wa1.x, xa, acc[4]); acc[5] = fmaf(wa1.y, xa, acc[5]);
      acc[6] = fmaf(wa1.z, xa, acc[6]); acc[7] = fmaf(wa1.w, xa, acc[7]);
    }
    __builtin_amdgcn_wave_barrier();   // WAR fence before next chunk's restage
  }
  // scale by 1/sum per head, pack, store (k-order d*8+h; lane = d)
  float4 i0 = *(const float4*)&sinv[wave][0];
  float4 i1 = *(const float4*)&sinv[wave][4];
  acc[0] *= i0.x; acc[1] *= i0.y; acc[2] *= i0.z; acc[3] *= i0.w;
  acc[4] *= i1.x; acc[5] *= i1.y; acc[6] *= i1.z; acc[7] *= i1.w;
  uint o[4];
#pragma unroll
  for (int i = 0; i < 4; ++i)
    o[i] = (uint)f2bf(acc[2 * i]) | ((uint)f2bf(acc[2 * i + 1]) << 16);
  *(uint4*)(aggx + (size_t)n * 512 + lane * 8) = make_uint4(o[0], o[1], o[2], o[3]);
}

// ---------------- Y = aggx(bf16) @ W'(bf16) + bias + res(bf16) via MFMA; fused LN stats ----------------
__global__ __launch_bounds__(256) void outgemm_stats_kernel(const ushort* __restrict__ A,
                                                            const ushort* __restrict__ BT,
                                                            const float* __restrict__ bias,
                                                            const ushort* __restrict__ res,
                                                            const int* __restrict__ batch,
                                                            float* __restrict__ Y,
                                                            float* __restrict__ gs,
                                                            float* __restrict__ gss){
  __shared__ ushort Al[64][136];  // +8 pad
  __shared__ ushort Bl[64][136];
  __shared__ float gsl[NG], gssl[NG];
  const int t = threadIdx.x;
  const int wave = t >> 6, lane = t & 63;
  const int rowbase = blockIdx.x * 64;
  const int frow = lane & 15, kc = lane >> 4;
  if (t < NG){ gsl[t] = 0.f; gssl[t] = 0.f; }
  f32x4 acc[4];
#pragma unroll
  for (int ct = 0; ct < 4; ++ct) acc[ct] = (f32x4){0.f, 0.f, 0.f, 0.f};

  for (int k0 = 0; k0 < 512; k0 += 128){
#pragma unroll
    for (int ppass = 0; ppass < 4; ++ppass){
      int idx = (ppass * 256 + t) * 8;
      int r = idx >> 7, k = idx & 127;
      int grow = rowbase + r;
      uint4 v = make_uint4(0u, 0u, 0u, 0u);
      if (grow < N_NODES) v = *(const uint4*)(A + (size_t)grow * 512 + k0 + k);
      *(uint4*)&Al[r][k] = v;
      uint4 w = *(const uint4*)(BT + (size_t)r * 512 + k0 + k);
      *(uint4*)&Bl[r][k] = w;
    }
    __syncthreads();
#pragma unroll
    for (int kf = 0; kf < 4; ++kf){
      bf16x8 a = *(const bf16x8*)&Al[wave * 16 + frow][kf * 32 + kc * 8];
#pragma unroll
      for (int ct = 0; ct < 4; ++ct){
        bf16x8 b = *(const bf16x8*)&Bl[ct * 16 + frow][kf * 32 + kc * 8];
        acc[ct] = __builtin_amdgcn_mfma_f32_16x16x32_bf16(a, b, acc[ct], 0, 0, 0);
      }
    }
    __syncthreads();
  }
  const int col0 = lane & 15, rsub = (lane >> 4) * 4;
  float rs[4] = {0.f, 0.f, 0.f, 0.f}, rss[4] = {0.f, 0.f, 0.f, 0.f};
#pragma unroll
  for (int ct = 0; ct < 4; ++ct){
    int col = ct * 16 + col0;
    float bs = bias[col];
#pragma unroll
    for (int j = 0; j < 4; ++j){
      int grow = rowbase + wave * 16 + rsub + j;
      if (grow < N_NODES){
        float y = acc[ct][j] + bs + bf2f(res[(size_t)grow * 64 + col]);
        Y[(size_t)grow * 64 + col] = y;
        rs[j] += y;
        rss[j] = fmaf(y, y, rss[j]);
      }
    }
  }
#pragma unroll
  for (int j = 0; j < 4; ++j){
#pragma unroll
    for (int off = 1; off < 16; off <<= 1){
      rs[j] += __shfl_xor(rs[j], off, 64);
      rss[j] += __shfl_xor(rss[j], off, 64);
    }
  }
  if (col0 == 0){
#pragma unroll
    for (int j = 0; j < 4; ++j){
      int grow = rowbase + wave * 16 + rsub + j;
      if (grow < N_NODES){
        int g = batch[grow];
        atomicAdd(&gsl[g], rs[j]);
        atomicAdd(&gssl[g], rss[j]);
      }
    }
  }
  __syncthreads();
  if (t < NG && (gsl[t] != 0.f || gssl[t] != 0.f)){
    atomicAdd(&gs[t], gsl[t]);
    atomicAdd(&gss[t], gssl[t]);
  }
}

// ---------------- layer1 normalize+relu + layer2 al, fused (bf16 output only) ----------------
__global__ __launch_bounds__(256) void norm_relu_al_kernel(const float* __restrict__ Y,
                                                           const int* __restrict__ batch,
                                                           const int* __restrict__ gstart,
                                                           const float* __restrict__ gs,
                                                           const float* __restrict__ gss,
                                                           const float* __restrict__ lw,
                                                           const float* __restrict__ lb,
                                                           const float* __restrict__ wa,
                                                           ushort* __restrict__ outb,
                                                           float* __restrict__ al){
  __shared__ float rows[4][64];
  const int t = threadIdx.x;
  const int nl = t >> 6, c = t & 63;
  const int n = blockIdx.x * 4 + nl;
  int g = batch[n];
  float cnt = (float)(gstart[g + 1] - gstart[g]);
  float norm = fmaxf(cnt, 1.f) * 64.f;
  float m = gs[g] / norm;
  float var = fmaxf(gss[g] / norm - m * m, 0.f);
  float rstd = rsqrtf(var + 1e-5f);
  float v = (Y[(size_t)n * 64 + c] - m) * rstd * lw[c] + lb[c];
  float r = fmaxf(v, 0.f);
  outb[(size_t)n * 64 + c] = f2bf(r);
  rows[nl][c] = r;
  __syncthreads();
  if (t < 64){
    int nn = t >> 4, cc = t & 15;
    float s = 0.f;
#pragma unroll
    for (int k = 0; k < 64; ++k) s = fmaf(rows[nn][k], wa[k * 16 + cc], s);
    al[(size_t)(blockIdx.x * 4 + nn) * 16 + cc] = s;
  }
}

// ---------------- normalize + relu + pooled accumulation (layer 2); inline finalize ----------------
__global__ void norm_relu_pool_kernel(const float* __restrict__ Y, const int* __restrict__ batch,
                                      const int* __restrict__ gstart, const float* __restrict__ gs,
                                      const float* __restrict__ gss,
                                      const float* __restrict__ lw, const float* __restrict__ lb,
                                      float* __restrict__ pooled){
  int w = (int)((blockIdx.x * blockDim.x + threadIdx.x) >> 6);
  int lane = threadIdx.x & 63;
  int nbase = w * 16;
  if (nbase >= N_NODES) return;
  int nend = min(nbase + 16, N_NODES);
  float accv = 0.f;
  int g = batch[nbase];
  float cnt = (float)(gstart[g + 1] - gstart[g]);
  float norm = fmaxf(cnt, 1.f) * 64.f;
  float m = gs[g] / norm;
  float var = fmaxf(gss[g] / norm - m * m, 0.f);
  float rstd = rsqrtf(var + 1e-5f);
  for (int n = nbase; n < nend; ++n){
    int gn = batch[n];
    if (gn != g){
      atomicAdd(&pooled[g * 64 + lane], accv);
      accv = 0.f; g = gn;
      cnt = (float)(gstart[g + 1] - gstart[g]);
      norm = fmaxf(cnt, 1.f) * 64.f;
      m = gs[g] / norm;
      var = fmaxf(gss[g] / norm - m * m, 0.f);
      rstd = rsqrtf(var + 1e-5f);
    }
    float v = (Y[(size_t)n * 64 + lane] - m) * rstd * lw[lane] + lb[lane];
    accv += fmaxf(v, 0.f);
  }
  atomicAdd(&pooled[g * 64 + lane], accv);
}

// ---------------- head ----------------
__global__ void head_kernel(const float* __restrict__ pooled, const int* __restrict__ gstart,
                            const float* __restrict__ Wh, const float* __restrict__ bh,
                            float* __restrict__ out){
  int idx = blockIdx.x * blockDim.x + threadIdx.x;
  if (idx >= NG * 32) return;
  int g = idx >> 5, o = idx & 31;
  float cnt = (float)(gstart[g + 1] - gstart[g]);
  float inv = 1.f / fmaxf(cnt, 1.f);
  float s = 0.f;
#pragma unroll
  for (int d = 0; d < 64; ++d) s = fmaf(pooled[g * 64 + d] * inv, Wh[d * 32 + o], s);
  out[idx] = fmaxf(s + bh[o], 0.f);
}

// ---------------- launch ----------------
extern "C" void kernel_launch(void* const* d_in, const int* in_sizes, int n_in,
                              void* d_out, int out_size, void* d_ws, size_t ws_size,
                              hipStream_t stream){
  const float* x     = (const float*)d_in[0];
  const int*   ei    = (const int*)d_in[1];
  const int*   batch = (const int*)d_in[2];
  const float* W1    = (const float*)d_in[3];
  const float* as1   = (const float*)d_in[4];
  const float* ad1   = (const float*)d_in[5];
  const float* b1    = (const float*)d_in[6];
  const float* l1w   = (const float*)d_in[7];
  const float* l1b   = (const float*)d_in[8];
  const float* W2    = (const float*)d_in[9];
  const float* as2   = (const float*)d_in[10];
  const float* ad2   = (const float*)d_in[11];
  const float* b2    = (const float*)d_in[12];
  const float* l2w   = (const float*)d_in[13];
  const float* l2b   = (const float*)d_in[14];
  const float* Wh    = (const float*)d_in[15];
  const float* bh    = (const float*)d_in[16];
  float* out = (float*)d_out;

  char* p = (char*)d_ws;
  auto alloc = [&](size_t bytes) -> void* {
    void* r = (void*)p;
    p += (bytes + 255) & ~(size_t)255;
    return r;
  };
  int*    counts   = (int*)alloc(N_NODES * 4);
  int*    cursor   = (int*)alloc(N_NODES * 4);   // adjacent to counts: one memset
  int*    row_off  = (int*)alloc((N_NODES + 1) * 4);
  int*    csr_src  = (int*)alloc(E_TOT * 4);
  int*    gstart   = (int*)alloc((NG + 1) * 4);
  int*    blocksum = (int*)alloc((SCAN_NB + 1) * 4);
  int*    blockoff = (int*)alloc((SCAN_NB + 1) * 4);
  float*  wa1      = (float*)alloc(64 * 16 * 4);
  float*  wa2      = (float*)alloc(64 * 16 * 4);
  ushort* w1pT     = (ushort*)alloc(64 * 512 * 2);
  ushort* w2pT     = (ushort*)alloc(64 * 512 * 2);
  float*  al       = (float*)alloc((size_t)N_NODES * 16 * 4);
  ushort* xbf      = (ushort*)alloc((size_t)N_NODES * 64 * 2);
  ushort* y1b      = (ushort*)alloc((size_t)N_NODES * 64 * 2);
  ushort* aggx     = (ushort*)alloc((size_t)N_NODES * 512 * 2);
  float*  y1p      = (float*)alloc((size_t)N_NODES * 64 * 4);
  float*  y2p      = y1p;  // y1p dead after layer-1 norm_relu_al
  float*  gstats   = (float*)alloc(8 * NG * 4);
  float*  pooled   = (float*)alloc(NG * 64 * 4);  // adjacent to gstats: one memset
  float* gs1 = gstats, *gss1 = gstats + NG, *gs2 = gstats + 2*NG, *gss2 = gstats + 3*NG;

  hipMemsetAsync(counts, 0, (size_t)((char*)row_off - (char*)counts), stream);
  hipMemsetAsync(gstats, 0, (size_t)((char*)pooled - (char*)gstats) + NG * 64 * 4, stream);

  // setup: prep + bounds + count in one kernel
  setup_kernel<<<(SETUP_TOTAL + 255) / 256, 256, 0, stream>>>(
      W1, as1, ad1, W2, as2, ad2, batch, ei, wa1, wa2, w1pT, w2pT, gstart, counts);

  // CSR scan + scatter
  scan1_kernel<<<SCAN_NB, SCAN_B, 0, stream>>>(counts, row_off, blocksum);
  scan2_kernel<<<1, 64, 0, stream>>>(blocksum, blockoff);
  scan3_kernel<<<(N_NODES + 255) / 256, 256, 0, stream>>>(row_off, blockoff);
  scatter_kernel<<<(E_TOT + 255) / 256, 256, 0, stream>>>(ei, row_off, cursor, csr_src);

  const int waggBlocks = N_NODES / 4;   // exactly 12500
  const int waveBlocks = ((N_NODES + 15) / 16 * 64 + 255) / 256;
  const int gemmBlocks = (N_NODES + 63) / 64;

  // ---- layer 1 ----
  al1_kernel<<<(N_NODES * 16 + 255) / 256, 256, 0, stream>>>(x, wa1, al, xbf);
  wagg_kernel<<<waggBlocks, 256, 0, stream>>>(xbf, al, row_off, csr_src, aggx);
  outgemm_stats_kernel<<<gemmBlocks, 256, 0, stream>>>(aggx, w1pT, b1, xbf, batch, y1p, gs1, gss1);
  norm_relu_al_kernel<<<waggBlocks, 256, 0, stream>>>(y1p, batch, gstart, gs1, gss1, l1w, l1b, wa2, y1b, al);

  // ---- layer 2 ----
  wagg_kernel<<<waggBlocks, 256, 0, stream>>>(y1b, al, row_off, csr_src, aggx);
  outgemm_stats_kernel<<<gemmBlocks, 256, 0, stream>>>(aggx, w2pT, b2, y1b, batch, y2p, gs2, gss2);
  norm_relu_pool_kernel<<<waveBlocks, 256, 0, stream>>>(y2p, batch, gstart, gs2, gss2, l2w, l2b, pooled);

  // ---- head ----
  head_kernel<<<(NG * 32 + 255) / 256, 256, 0, stream>>>(pooled, gstart, Wh, bh, out);
}

// Round 13
// 242.743 us; speedup vs baseline: 1.1046x; 1.1046x over previous
//
#include <hip/hip_runtime.h>
#include <math.h>

#define N_NODES 50000
#define N_EDGES 400000
#define E_TOT   (N_EDGES + N_NODES)
#define NG      64
#define NEG_SLOPE 0.2f

typedef __attribute__((ext_vector_type(8))) short bf16x8;
typedef __attribute__((ext_vector_type(4))) float f32x4;

// ---------------- helpers ----------------
__device__ __forceinline__ float lrelu(float x){ return x > 0.f ? x : NEG_SLOPE * x; }
__device__ __forceinline__ ushort f2bf(float f){
  union { float f; unsigned u; } v; v.f = f;
  unsigned r = v.u + 0x7FFFu + ((v.u >> 16) & 1u);  // RNE
  return (ushort)(r >> 16);
}
__device__ __forceinline__ float bf2f(ushort u){
  return __uint_as_float(((unsigned)u) << 16);
}

// ---------------- setup: prep weights + graph bounds + edge count, ONE kernel ----------------
#define SETUP_PREP   (2048 + 2 * 32768)
#define SETUP_BOUNDS (SETUP_PREP + N_NODES + 1)
#define SETUP_TOTAL  (SETUP_BOUNDS + E_TOT)

__global__ void setup_kernel(const float* __restrict__ W1, const float* __restrict__ as1,
                             const float* __restrict__ ad1, const float* __restrict__ W2,
                             const float* __restrict__ as2, const float* __restrict__ ad2,
                             const int* __restrict__ batch, const int* __restrict__ ei,
                             float* __restrict__ wa1, float* __restrict__ wa2,
                             ushort* __restrict__ w1pT, ushort* __restrict__ w2pT,
                             int* __restrict__ gstart, int* __restrict__ counts){
  int idx = blockIdx.x * blockDim.x + threadIdx.x;
  if (idx < 2048){
    const float* W = (idx < 1024) ? W1 : W2;
    const float* asr = (idx < 1024) ? as1 : as2;
    const float* adr = (idx < 1024) ? ad1 : ad2;
    float* wa = (idx < 1024) ? wa1 : wa2;
    int i = idx & 1023;
    int k = i >> 4, c = i & 15;
    int h = c & 7;
    const float* a = (c < 8) ? asr : adr;
    float s = 0.f;
#pragma unroll
    for (int d = 0; d < 64; ++d) s = fmaf(W[k * 512 + h * 64 + d], a[h * 64 + d], s);
    wa[i] = s;
  } else if (idx < SETUP_PREP){
    int i = idx - 2048;
    const float* W = (i < 32768) ? W1 : W2;
    ushort* wpT = (i < 32768) ? w1pT : w2pT;
    i &= 32767;
    // k-order = d*8 + h (matches wagg's packed store)
    int j = i >> 9, k = i & 511;
    int d = k >> 3, h = k & 7;
    wpT[i] = f2bf(W[d * 512 + h * 64 + j] * 0.125f);
  } else if (idx < SETUP_BOUNDS){
    int n = idx - SETUP_PREP;
    int g = (n < N_NODES) ? batch[n] : NG;
    if (n == 0){
      for (int gg = 0; gg <= g; ++gg) gstart[gg] = 0;
    } else {
      int gp = batch[n - 1];
      for (int gg = gp + 1; gg <= g; ++gg) gstart[gg] = n;
    }
  } else if (idx < SETUP_TOTAL){
    int e = idx - SETUP_BOUNDS;
    int dst = (e < N_EDGES) ? ei[N_EDGES + e] : (e - N_EDGES);
    atomicAdd(&counts[dst], 1);
  }
}

// ---------- two-level exclusive scan of counts[N_NODES] -> row_off ----------
#define SCAN_B 1024
#define SCAN_NB ((N_NODES + SCAN_B - 1) / SCAN_B)   // 49

__global__ __launch_bounds__(SCAN_B) void scan1_kernel(const int* __restrict__ counts,
                                                       int* __restrict__ row_off,
                                                       int* __restrict__ blocksum){
  __shared__ int sh[SCAN_B];
  int i = blockIdx.x * SCAN_B + threadIdx.x;
  int v = (i < N_NODES) ? counts[i] : 0;
  sh[threadIdx.x] = v;
  __syncthreads();
#pragma unroll
  for (int off = 1; off < SCAN_B; off <<= 1){
    int add = (threadIdx.x >= (unsigned)off) ? sh[threadIdx.x - off] : 0;
    __syncthreads();
    sh[threadIdx.x] += add;
    __syncthreads();
  }
  if (i < N_NODES) row_off[i] = sh[threadIdx.x] - v;
  if (threadIdx.x == SCAN_B - 1) blocksum[blockIdx.x] = sh[SCAN_B - 1];
}

__global__ void scan2_kernel(int* __restrict__ blocksum, int* __restrict__ blockoff){
  __shared__ int sh[64];
  int t = threadIdx.x;
  int v = (t < SCAN_NB) ? blocksum[t] : 0;
  sh[t] = v;
  __syncthreads();
#pragma unroll
  for (int off = 1; off < 64; off <<= 1){
    int add = (t >= off) ? sh[t - off] : 0;
    __syncthreads();
    sh[t] += add;
    __syncthreads();
  }
  if (t < SCAN_NB) blockoff[t] = sh[t] - v;
  if (t == 63) blockoff[SCAN_NB] = sh[63];
}

__global__ void scan3_kernel(int* __restrict__ row_off, const int* __restrict__ blockoff){
  int i = blockIdx.x * blockDim.x + threadIdx.x;
  if (i < N_NODES) row_off[i] += blockoff[i >> 10];
  if (i == 0) row_off[N_NODES] = blockoff[SCAN_NB];
}

__global__ void scatter_kernel(const int* __restrict__ ei, const int* __restrict__ row_off,
                               int* __restrict__ cursor, int* __restrict__ csr_src){
  int e = blockIdx.x * blockDim.x + threadIdx.x;
  if (e >= E_TOT) return;
  int src, dst;
  if (e < N_EDGES){ src = ei[e]; dst = ei[N_EDGES + e]; }
  else            { src = dst = e - N_EDGES; }
  int pos = row_off[dst] + atomicAdd(&cursor[dst], 1);
  csr_src[pos] = src;
}

// ---------------- layer1 al from f32 x; also emits x as bf16 ----------------
__global__ void al1_kernel(const float* __restrict__ xin, const float* __restrict__ wa,
                           float* __restrict__ al, ushort* __restrict__ xbf){
  __shared__ float w[64 * 16];
  for (int i = threadIdx.x; i < 1024; i += blockDim.x) w[i] = wa[i];
  __syncthreads();
  int idx = blockIdx.x * blockDim.x + threadIdx.x;
  if (idx >= N_NODES * 16) return;
  int n = idx >> 4, c = idx & 15;
  const float* xr = xin + (size_t)n * 64;
  float s = 0.f;
#pragma unroll
  for (int k4 = 0; k4 < 16; ++k4){
    float4 v = *(const float4*)(xr + k4 * 4);
    s = fmaf(v.x, w[(k4 * 4 + 0) * 16 + c], s);
    s = fmaf(v.y, w[(k4 * 4 + 1) * 16 + c], s);
    s = fmaf(v.z, w[(k4 * 4 + 2) * 16 + c], s);
    s = fmaf(v.w, w[(k4 * 4 + 3) * 16 + c], s);
  }
  float4 mine = *(const float4*)(xr + c * 4);
  ushort ob[4] = {f2bf(mine.x), f2bf(mine.y), f2bf(mine.z), f2bf(mine.w)};
  *(ushort4*)(xbf + (size_t)n * 64 + c * 4) = *(const ushort4*)ob;
  al[idx] = s;
}

// ---------------- FUSED softmax weights + aggregation (v6: R11 body, persistent waves) ----------------
// Barrier-free wave-private LDS staging; each wave grid-strides over nodes.
__global__ __launch_bounds__(256) void wagg_kernel(const ushort* __restrict__ xb,
                                                   const float* __restrict__ al,
                                                   const int* __restrict__ row_off,
                                                   const int* __restrict__ csr_src,
                                                   ushort* __restrict__ aggx){
  __shared__ float ws[4][64][8];   // 8 KB, wave-private slices
  const int wave = threadIdx.x >> 6, lane = threadIdx.x & 63;
  const int eo = lane >> 3, h = lane & 7;
  const int stride = gridDim.x * 4;

  for (int n = blockIdx.x * 4 + wave; n < N_NODES; n += stride){
    const int s0 = row_off[n], s1 = row_off[n + 1];
    const int deg = s1 - s0;
    const float ald = al[n * 16 + 8 + h];

    // one load covers this node's first 64 src indices
    int idxv = (s0 + lane < s1) ? csr_src[s0 + lane] : 0;

    const bool fast = (deg <= 64);
    float wv[8];
    float sum = 0.f;
    if (fast){
#pragma unroll
      for (int i = 0; i < 8; ++i){
        int ee = eo + i * 8;
        int s = __shfl(idxv, ee, 64);
        float v = 0.f;
        if (ee < deg) v = __expf(lrelu(al[s * 16 + h] + ald));
        wv[i] = v; sum += v;
      }
    } else {
      for (int e = s0 + eo; e < s1; e += 8){
        int s = csr_src[e];
        sum += __expf(lrelu(al[s * 16 + h] + ald));
      }
    }
#pragma unroll
    for (int off = 8; off < 64; off <<= 1) sum += __shfl_xor(sum, off, 64);
    const float inv = 1.f / (sum + 1e-16f);

    float acc[8];
#pragma unroll
    for (int i = 0; i < 8; ++i) acc[i] = 0.f;

    const int nchunk = (deg + 63) >> 6;   // per-wave: no cross-wave coupling
    for (int c = 0; c < nchunk; ++c){
      const int base = s0 + c * 64;
      // phase 1: stage normalized weights (f32) for this chunk (wave-private)
      if (fast){
        if (c == 0){
#pragma unroll
          for (int i = 0; i < 8; ++i){
            int ee = eo + i * 8;
            if (ee < deg) ws[wave][ee][h] = wv[i] * inv;
          }
        }
      } else {
#pragma unroll
        for (int i = 0; i < 8; ++i){
          int e = base + eo + i * 8;
          if (e < s1){
            int s = csr_src[e];
            ws[wave][e - base][h] = __expf(lrelu(al[s * 16 + h] + ald)) * inv;
          }
        }
      }
      __builtin_amdgcn_wave_barrier();   // no reorder of reads above writes
      // phase 2: aggregate this chunk (lane = dim)
      const int cend = min(base + 64, s1);
      int e = base;
      for (; e + 4 <= cend; e += 4){
        int r0 = e - base;
        int sa, sb, sc, sd;
        if (fast){
          sa = __shfl(idxv, e - s0, 64);
          sb = __shfl(idxv, e - s0 + 1, 64);
          sc = __shfl(idxv, e - s0 + 2, 64);
          sd = __shfl(idxv, e - s0 + 3, 64);
        } else {
          sa = csr_src[e]; sb = csr_src[e + 1]; sc = csr_src[e + 2]; sd = csr_src[e + 3];
        }
        float xa = bf2f(xb[(size_t)sa * 64 + lane]);
        float xc = bf2f(xb[(size_t)sb * 64 + lane]);
        float xe = bf2f(xb[(size_t)sc * 64 + lane]);
        float xg = bf2f(xb[(size_t)sd * 64 + lane]);
        float4 wa0 = *(const float4*)&ws[wave][r0][0];
        float4 wa1 = *(const float4*)&ws[wave][r0][4];
        float4 wb0 = *(const float4*)&ws[wave][r0 + 1][0];
        float4 wb1 = *(const float4*)&ws[wave][r0 + 1][4];
        float4 wc0 = *(const float4*)&ws[wave][r0 + 2][0];
        float4 wc1 = *(const float4*)&ws[wave][r0 + 2][4];
        float4 wd0 = *(const float4*)&ws[wave][r0 + 3][0];
        float4 wd1 = *(const float4*)&ws[wave][r0 + 3][4];
        acc[0] = fmaf(wa0.x, xa, acc[0]); acc[1] = fmaf(wa0.y, xa, acc[1]);
        acc[2] = fmaf(wa0.z, xa, acc[2]); acc[3] = fmaf(wa0.w, xa, acc[3]);
        acc[4] = fmaf(wa1.x, xa, acc[4]); acc[5] = fmaf(wa1.y, xa, acc[5]);
        acc[6] = fmaf(wa1.z, xa, acc[6]); acc[7] = fmaf(wa1.w, xa, acc[7]);
        acc[0] = fmaf(wb0.x, xc, acc[0]); acc[1] = fmaf(wb0.y, xc, acc[1]);
        acc[2] = fmaf(wb0.z, xc, acc[2]); acc[3] = fmaf(wb0.w, xc, acc[3]);
        acc[4] = fmaf(wb1.x, xc, acc[4]); acc[5] = fmaf(wb1.y, xc, acc[5]);
        acc[6] = fmaf(wb1.z, xc, acc[6]); acc[7] = fmaf(wb1.w, xc, acc[7]);
        acc[0] = fmaf(wc0.x, xe, acc[0]); acc[1] = fmaf(wc0.y, xe, acc[1]);
        acc[2] = fmaf(wc0.z, xe, acc[2]); acc[3] = fmaf(wc0.w, xe, acc[3]);
        acc[4] = fmaf(wc1.x, xe, acc[4]); acc[5] = fmaf(wc1.y, xe, acc[5]);
        acc[6] = fmaf(wc1.z, xe, acc[6]); acc[7] = fmaf(wc1.w, xe, acc[7]);
        acc[0] = fmaf(wd0.x, xg, acc[0]); acc[1] = fmaf(wd0.y, xg, acc[1]);
        acc[2] = fmaf(wd0.z, xg, acc[2]); acc[3] = fmaf(wd0.w, xg, acc[3]);
        acc[4] = fmaf(wd1.x, xg, acc[4]); acc[5] = fmaf(wd1.y, xg, acc[5]);
        acc[6] = fmaf(wd1.z, xg, acc[6]); acc[7] = fmaf(wd1.w, xg, acc[7]);
      }
      for (; e < cend; ++e){
        int r0 = e - base;
        int sa = fast ? __shfl(idxv, e - s0, 64) : csr_src[e];
        float xa = bf2f(xb[(size_t)sa * 64 + lane]);
        float4 wa0 = *(const float4*)&ws[wave][r0][0];
        float4 wa1 = *(const float4*)&ws[wave][r0][4];
        acc[0] = fmaf(wa0.x, xa, acc[0]); acc[1] = fmaf(wa0.y, xa, acc[1]);
        acc[2] = fmaf(wa0.z, xa, acc[2]); acc[3] = fmaf(wa0.w, xa, acc[3]);
        acc[4] = fmaf(wa1.x, xa, acc[4]); acc[5] = fmaf(wa1.y, xa, acc[5]);
        acc[6] = fmaf(wa1.z, xa, acc[6]); acc[7] = fmaf(wa1.w, xa, acc[7]);
      }
      __builtin_amdgcn_wave_barrier();   // WAR fence before next chunk's restage
    }
    // packed store: k-order d*8+h, lane=d owns 8 consecutive bf16 = 16B
    uint o[4];
#pragma unroll
    for (int i = 0; i < 4; ++i)
      o[i] = (uint)f2bf(acc[2 * i]) | ((uint)f2bf(acc[2 * i + 1]) << 16);
    *(uint4*)(aggx + (size_t)n * 512 + lane * 8) = make_uint4(o[0], o[1], o[2], o[3]);
    __builtin_amdgcn_wave_barrier();   // keep iterations from interleaving LDS reuse
  }
}

// ---------------- Y = aggx(bf16) @ W'(bf16) + bias + res(bf16) via MFMA; fused LN stats ----------------
__global__ __launch_bounds__(256) void outgemm_stats_kernel(const ushort* __restrict__ A,
                                                            const ushort* __restrict__ BT,
                                                            const float* __restrict__ bias,
                                                            const ushort* __restrict__ res,
                                                            const int* __restrict__ batch,
                                                            float* __restrict__ Y,
                                                            float* __restrict__ gs,
                                                            float* __restrict__ gss){
  __shared__ ushort Al[64][136];  // +8 pad
  __shared__ ushort Bl[64][136];
  __shared__ float gsl[NG], gssl[NG];
  const int t = threadIdx.x;
  const int wave = t >> 6, lane = t & 63;
  const int rowbase = blockIdx.x * 64;
  const int frow = lane & 15, kc = lane >> 4;
  if (t < NG){ gsl[t] = 0.f; gssl[t] = 0.f; }
  f32x4 acc[4];
#pragma unroll
  for (int ct = 0; ct < 4; ++ct) acc[ct] = (f32x4){0.f, 0.f, 0.f, 0.f};

  for (int k0 = 0; k0 < 512; k0 += 128){
#pragma unroll
    for (int ppass = 0; ppass < 4; ++ppass){
      int idx = (ppass * 256 + t) * 8;
      int r = idx >> 7, k = idx & 127;
      int grow = rowbase + r;
      uint4 v = make_uint4(0u, 0u, 0u, 0u);
      if (grow < N_NODES) v = *(const uint4*)(A + (size_t)grow * 512 + k0 + k);
      *(uint4*)&Al[r][k] = v;
      uint4 w = *(const uint4*)(BT + (size_t)r * 512 + k0 + k);
      *(uint4*)&Bl[r][k] = w;
    }
    __syncthreads();
#pragma unroll
    for (int kf = 0; kf < 4; ++kf){
      bf16x8 a = *(const bf16x8*)&Al[wave * 16 + frow][kf * 32 + kc * 8];
#pragma unroll
      for (int ct = 0; ct < 4; ++ct){
        bf16x8 b = *(const bf16x8*)&Bl[ct * 16 + frow][kf * 32 + kc * 8];
        acc[ct] = __builtin_amdgcn_mfma_f32_16x16x32_bf16(a, b, acc[ct], 0, 0, 0);
      }
    }
    __syncthreads();
  }
  const int col0 = lane & 15, rsub = (lane >> 4) * 4;
  float rs[4] = {0.f, 0.f, 0.f, 0.f}, rss[4] = {0.f, 0.f, 0.f, 0.f};
#pragma unroll
  for (int ct = 0; ct < 4; ++ct){
    int col = ct * 16 + col0;
    float bs = bias[col];
#pragma unroll
    for (int j = 0; j < 4; ++j){
      int grow = rowbase + wave * 16 + rsub + j;
      if (grow < N_NODES){
        float y = acc[ct][j] + bs + bf2f(res[(size_t)grow * 64 + col]);
        Y[(size_t)grow * 64 + col] = y;
        rs[j] += y;
        rss[j] = fmaf(y, y, rss[j]);
      }
    }
  }
#pragma unroll
  for (int j = 0; j < 4; ++j){
#pragma unroll
    for (int off = 1; off < 16; off <<= 1){
      rs[j] += __shfl_xor(rs[j], off, 64);
      rss[j] += __shfl_xor(rss[j], off, 64);
    }
  }
  if (col0 == 0){
#pragma unroll
    for (int j = 0; j < 4; ++j){
      int grow = rowbase + wave * 16 + rsub + j;
      if (grow < N_NODES){
        int g = batch[grow];
        atomicAdd(&gsl[g], rs[j]);
        atomicAdd(&gssl[g], rss[j]);
      }
    }
  }
  __syncthreads();
  if (t < NG && (gsl[t] != 0.f || gssl[t] != 0.f)){
    atomicAdd(&gs[t], gsl[t]);
    atomicAdd(&gss[t], gssl[t]);
  }
}

// ---------------- layer1 normalize+relu + layer2 al, fused (bf16 output only) ----------------
__global__ __launch_bounds__(256) void norm_relu_al_kernel(const float* __restrict__ Y,
                                                           const int* __restrict__ batch,
                                                           const int* __restrict__ gstart,
                                                           const float* __restrict__ gs,
                                                           const float* __restrict__ gss,
                                                           const float* __restrict__ lw,
                                                           const float* __restrict__ lb,
                                                           const float* __restrict__ wa,
                                                           ushort* __restrict__ outb,
                                                           float* __restrict__ al){
  __shared__ float rows[4][64];
  const int t = threadIdx.x;
  const int nl = t >> 6, c = t & 63;
  const int n = blockIdx.x * 4 + nl;
  int g = batch[n];
  float cnt = (float)(gstart[g + 1] - gstart[g]);
  float norm = fmaxf(cnt, 1.f) * 64.f;
  float m = gs[g] / norm;
  float var = fmaxf(gss[g] / norm - m * m, 0.f);
  float rstd = rsqrtf(var + 1e-5f);
  float v = (Y[(size_t)n * 64 + c] - m) * rstd * lw[c] + lb[c];
  float r = fmaxf(v, 0.f);
  outb[(size_t)n * 64 + c] = f2bf(r);
  rows[nl][c] = r;
  __syncthreads();
  if (t < 64){
    int nn = t >> 4, cc = t & 15;
    float s = 0.f;
#pragma unroll
    for (int k = 0; k < 64; ++k) s = fmaf(rows[nn][k], wa[k * 16 + cc], s);
    al[(size_t)(blockIdx.x * 4 + nn) * 16 + cc] = s;
  }
}

// ---------------- normalize + relu + pooled accumulation (layer 2); inline finalize ----------------
__global__ void norm_relu_pool_kernel(const float* __restrict__ Y, const int* __restrict__ batch,
                                      const int* __restrict__ gstart, const float* __restrict__ gs,
                                      const float* __restrict__ gss,
                                      const float* __restrict__ lw, const float* __restrict__ lb,
                                      float* __restrict__ pooled){
  int w = (int)((blockIdx.x * blockDim.x + threadIdx.x) >> 6);
  int lane = threadIdx.x & 63;
  int nbase = w * 16;
  if (nbase >= N_NODES) return;
  int nend = min(nbase + 16, N_NODES);
  float accv = 0.f;
  int g = batch[nbase];
  float cnt = (float)(gstart[g + 1] - gstart[g]);
  float norm = fmaxf(cnt, 1.f) * 64.f;
  float m = gs[g] / norm;
  float var = fmaxf(gss[g] / norm - m * m, 0.f);
  float rstd = rsqrtf(var + 1e-5f);
  for (int n = nbase; n < nend; ++n){
    int gn = batch[n];
    if (gn != g){
      atomicAdd(&pooled[g * 64 + lane], accv);
      accv = 0.f; g = gn;
      cnt = (float)(gstart[g + 1] - gstart[g]);
      norm = fmaxf(cnt, 1.f) * 64.f;
      m = gs[g] / norm;
      var = fmaxf(gss[g] / norm - m * m, 0.f);
      rstd = rsqrtf(var + 1e-5f);
    }
    float v = (Y[(size_t)n * 64 + lane] - m) * rstd * lw[lane] + lb[lane];
    accv += fmaxf(v, 0.f);
  }
  atomicAdd(&pooled[g * 64 + lane], accv);
}

// ---------------- head ----------------
__global__ void head_kernel(const float* __restrict__ pooled, const int* __restrict__ gstart,
                            const float* __restrict__ Wh, const float* __restrict__ bh,
                            float* __restrict__ out){
  int idx = blockIdx.x * blockDim.x + threadIdx.x;
  if (idx >= NG * 32) return;
  int g = idx >> 5, o = idx & 31;
  float cnt = (float)(gstart[g + 1] - gstart[g]);
  float inv = 1.f / fmaxf(cnt, 1.f);
  float s = 0.f;
#pragma unroll
  for (int d = 0; d < 64; ++d) s = fmaf(pooled[g * 64 + d] * inv, Wh[d * 32 + o], s);
  out[idx] = fmaxf(s + bh[o], 0.f);
}

// ---------------- launch ----------------
extern "C" void kernel_launch(void* const* d_in, const int* in_sizes, int n_in,
                              void* d_out, int out_size, void* d_ws, size_t ws_size,
                              hipStream_t stream){
  const float* x     = (const float*)d_in[0];
  const int*   ei    = (const int*)d_in[1];
  const int*   batch = (const int*)d_in[2];
  const float* W1    = (const float*)d_in[3];
  const float* as1   = (const float*)d_in[4];
  const float* ad1   = (const float*)d_in[5];
  const float* b1    = (const float*)d_in[6];
  const float* l1w   = (const float*)d_in[7];
  const float* l1b   = (const float*)d_in[8];
  const float* W2    = (const float*)d_in[9];
  const float* as2   = (const float*)d_in[10];
  const float* ad2   = (const float*)d_in[11];
  const float* b2    = (const float*)d_in[12];
  const float* l2w   = (const float*)d_in[13];
  const float* l2b   = (const float*)d_in[14];
  const float* Wh    = (const float*)d_in[15];
  const float* bh    = (const float*)d_in[16];
  float* out = (float*)d_out;

  char* p = (char*)d_ws;
  auto alloc = [&](size_t bytes) -> void* {
    void* r = (void*)p;
    p += (bytes + 255) & ~(size_t)255;
    return r;
  };
  int*    counts   = (int*)alloc(N_NODES * 4);
  int*    cursor   = (int*)alloc(N_NODES * 4);   // adjacent to counts: one memset
  int*    row_off  = (int*)alloc((N_NODES + 1) * 4);
  int*    csr_src  = (int*)alloc(E_TOT * 4);
  int*    gstart   = (int*)alloc((NG + 1) * 4);
  int*    blocksum = (int*)alloc((SCAN_NB + 1) * 4);
  int*    blockoff = (int*)alloc((SCAN_NB + 1) * 4);
  float*  wa1      = (float*)alloc(64 * 16 * 4);
  float*  wa2      = (float*)alloc(64 * 16 * 4);
  ushort* w1pT     = (ushort*)alloc(64 * 512 * 2);
  ushort* w2pT     = (ushort*)alloc(64 * 512 * 2);
  float*  al       = (float*)alloc((size_t)N_NODES * 16 * 4);
  ushort* xbf      = (ushort*)alloc((size_t)N_NODES * 64 * 2);
  ushort* y1b      = (ushort*)alloc((size_t)N_NODES * 64 * 2);
  ushort* aggx     = (ushort*)alloc((size_t)N_NODES * 512 * 2);
  float*  y1p      = (float*)alloc((size_t)N_NODES * 64 * 4);
  float*  y2p      = y1p;  // y1p dead after layer-1 norm_relu_al
  float*  gstats   = (float*)alloc(8 * NG * 4);
  float*  pooled   = (float*)alloc(NG * 64 * 4);  // adjacent to gstats: one memset
  float* gs1 = gstats, *gss1 = gstats + NG, *gs2 = gstats + 2*NG, *gss2 = gstats + 3*NG;

  hipMemsetAsync(counts, 0, (size_t)((char*)row_off - (char*)counts), stream);
  hipMemsetAsync(gstats, 0, (size_t)((char*)pooled - (char*)gstats) + NG * 64 * 4, stream);

  // setup: prep + bounds + count in one kernel
  setup_kernel<<<(SETUP_TOTAL + 255) / 256, 256, 0, stream>>>(
      W1, as1, ad1, W2, as2, ad2, batch, ei, wa1, wa2, w1pT, w2pT, gstart, counts);

  // CSR scan + scatter
  scan1_kernel<<<SCAN_NB, SCAN_B, 0, stream>>>(counts, row_off, blocksum);
  scan2_kernel<<<1, 64, 0, stream>>>(blocksum, blockoff);
  scan3_kernel<<<(N_NODES + 255) / 256, 256, 0, stream>>>(row_off, blockoff);
  scatter_kernel<<<(E_TOT + 255) / 256, 256, 0, stream>>>(ei, row_off, cursor, csr_src);

  const int waggBlocks = 2048;          // persistent waves, grid-stride over nodes
  const int nralBlocks = N_NODES / 4;   // exactly 12500
  const int waveBlocks = ((N_NODES + 15) / 16 * 64 + 255) / 256;
  const int gemmBlocks = (N_NODES + 63) / 64;

  // ---- layer 1 ----
  al1_kernel<<<(N_NODES * 16 + 255) / 256, 256, 0, stream>>>(x, wa1, al, xbf);
  wagg_kernel<<<waggBlocks, 256, 0, stream>>>(xbf, al, row_off, csr_src, aggx);
  outgemm_stats_kernel<<<gemmBlocks, 256, 0, stream>>>(aggx, w1pT, b1, xbf, batch, y1p, gs1, gss1);
  norm_relu_al_kernel<<<nralBlocks, 256, 0, stream>>>(y1p, batch, gstart, gs1, gss1, l1w, l1b, wa2, y1b, al);

  // ---- layer 2 ----
  wagg_kernel<<<waggBlocks, 256, 0, stream>>>(y1b, al, row_off, csr_src, aggx);
  outgemm_stats_kernel<<<gemmBlocks, 256, 0, stream>>>(aggx, w2pT, b2, y1b, batch, y2p, gs2, gss2);
  norm_relu_pool_kernel<<<waveBlocks, 256, 0, stream>>>(y2p, batch, gstart, gs2, gss2, l2w, l2b, pooled);

  // ---- head ----
  head_kernel<<<(NG * 32 + 255) / 256, 256, 0, stream>>>(pooled, gstart, Wh, bh, out);
}

// Round 14
// 223.592 us; speedup vs baseline: 1.1992x; 1.0857x over previous
//
#include <hip/hip_runtime.h>
#include <math.h>

#define N_NODES 50000
#define N_EDGES 400000
#define E_TOT   (N_EDGES + N_NODES)
#define NG      64
#define NEG_SLOPE 0.2f

typedef __attribute__((ext_vector_type(8))) short bf16x8;
typedef __attribute__((ext_vector_type(4))) float f32x4;

// ---------------- helpers ----------------
__device__ __forceinline__ float lrelu(float x){ return x > 0.f ? x : NEG_SLOPE * x; }
__device__ __forceinline__ ushort f2bf(float f){
  union { float f; unsigned u; } v; v.f = f;
  unsigned r = v.u + 0x7FFFu + ((v.u >> 16) & 1u);  // RNE
  return (ushort)(r >> 16);
}
__device__ __forceinline__ float bf2f(ushort u){
  return __uint_as_float(((unsigned)u) << 16);
}

// ---------------- setup: prep weights + graph bounds + edge count, ONE kernel ----------------
#define SETUP_PREP   (2048 + 2 * 32768)
#define SETUP_BOUNDS (SETUP_PREP + N_NODES + 1)
#define SETUP_TOTAL  (SETUP_BOUNDS + E_TOT)

__global__ void setup_kernel(const float* __restrict__ W1, const float* __restrict__ as1,
                             const float* __restrict__ ad1, const float* __restrict__ W2,
                             const float* __restrict__ as2, const float* __restrict__ ad2,
                             const int* __restrict__ batch, const int* __restrict__ ei,
                             float* __restrict__ wa1, float* __restrict__ wa2,
                             ushort* __restrict__ w1pT, ushort* __restrict__ w2pT,
                             int* __restrict__ gstart, int* __restrict__ counts){
  int idx = blockIdx.x * blockDim.x + threadIdx.x;
  if (idx < 2048){
    const float* W = (idx < 1024) ? W1 : W2;
    const float* asr = (idx < 1024) ? as1 : as2;
    const float* adr = (idx < 1024) ? ad1 : ad2;
    float* wa = (idx < 1024) ? wa1 : wa2;
    int i = idx & 1023;
    int k = i >> 4, c = i & 15;
    int h = c & 7;
    const float* a = (c < 8) ? asr : adr;
    float s = 0.f;
#pragma unroll
    for (int d = 0; d < 64; ++d) s = fmaf(W[k * 512 + h * 64 + d], a[h * 64 + d], s);
    wa[i] = s;
  } else if (idx < SETUP_PREP){
    int i = idx - 2048;
    const float* W = (i < 32768) ? W1 : W2;
    ushort* wpT = (i < 32768) ? w1pT : w2pT;
    i &= 32767;
    // k-order = d*8 + h (matches wagg's packed store)
    int j = i >> 9, k = i & 511;
    int d = k >> 3, h = k & 7;
    wpT[i] = f2bf(W[d * 512 + h * 64 + j] * 0.125f);
  } else if (idx < SETUP_BOUNDS){
    int n = idx - SETUP_PREP;
    int g = (n < N_NODES) ? batch[n] : NG;
    if (n == 0){
      for (int gg = 0; gg <= g; ++gg) gstart[gg] = 0;
    } else {
      int gp = batch[n - 1];
      for (int gg = gp + 1; gg <= g; ++gg) gstart[gg] = n;
    }
  } else if (idx < SETUP_TOTAL){
    int e = idx - SETUP_BOUNDS;
    int dst = (e < N_EDGES) ? ei[N_EDGES + e] : (e - N_EDGES);
    atomicAdd(&counts[dst], 1);
  }
}

// ---------- two-level exclusive scan of counts[N_NODES] -> row_off ----------
#define SCAN_B 1024
#define SCAN_NB ((N_NODES + SCAN_B - 1) / SCAN_B)   // 49

__global__ __launch_bounds__(SCAN_B) void scan1_kernel(const int* __restrict__ counts,
                                                       int* __restrict__ row_off,
                                                       int* __restrict__ blocksum){
  __shared__ int sh[SCAN_B];
  int i = blockIdx.x * SCAN_B + threadIdx.x;
  int v = (i < N_NODES) ? counts[i] : 0;
  sh[threadIdx.x] = v;
  __syncthreads();
#pragma unroll
  for (int off = 1; off < SCAN_B; off <<= 1){
    int add = (threadIdx.x >= (unsigned)off) ? sh[threadIdx.x - off] : 0;
    __syncthreads();
    sh[threadIdx.x] += add;
    __syncthreads();
  }
  if (i < N_NODES) row_off[i] = sh[threadIdx.x] - v;
  if (threadIdx.x == SCAN_B - 1) blocksum[blockIdx.x] = sh[SCAN_B - 1];
}

__global__ void scan2_kernel(int* __restrict__ blocksum, int* __restrict__ blockoff){
  __shared__ int sh[64];
  int t = threadIdx.x;
  int v = (t < SCAN_NB) ? blocksum[t] : 0;
  sh[t] = v;
  __syncthreads();
#pragma unroll
  for (int off = 1; off < 64; off <<= 1){
    int add = (t >= off) ? sh[t - off] : 0;
    __syncthreads();
    sh[t] += add;
    __syncthreads();
  }
  if (t < SCAN_NB) blockoff[t] = sh[t] - v;
  if (t == 63) blockoff[SCAN_NB] = sh[63];
}

__global__ void scan3_kernel(int* __restrict__ row_off, const int* __restrict__ blockoff){
  int i = blockIdx.x * blockDim.x + threadIdx.x;
  if (i < N_NODES) row_off[i] += blockoff[i >> 10];
  if (i == 0) row_off[N_NODES] = blockoff[SCAN_NB];
}

__global__ void scatter_kernel(const int* __restrict__ ei, const int* __restrict__ row_off,
                               int* __restrict__ cursor, int* __restrict__ csr_src){
  int e = blockIdx.x * blockDim.x + threadIdx.x;
  if (e >= E_TOT) return;
  int src, dst;
  if (e < N_EDGES){ src = ei[e]; dst = ei[N_EDGES + e]; }
  else            { src = dst = e - N_EDGES; }
  int pos = row_off[dst] + atomicAdd(&cursor[dst], 1);
  csr_src[pos] = src;
}

// ---------------- layer1 al from f32 x; also emits x as bf16 ----------------
__global__ void al1_kernel(const float* __restrict__ xin, const float* __restrict__ wa,
                           float* __restrict__ al, ushort* __restrict__ xbf){
  __shared__ float w[64 * 16];
  for (int i = threadIdx.x; i < 1024; i += blockDim.x) w[i] = wa[i];
  __syncthreads();
  int idx = blockIdx.x * blockDim.x + threadIdx.x;
  if (idx >= N_NODES * 16) return;
  int n = idx >> 4, c = idx & 15;
  const float* xr = xin + (size_t)n * 64;
  float s = 0.f;
#pragma unroll
  for (int k4 = 0; k4 < 16; ++k4){
    float4 v = *(const float4*)(xr + k4 * 4);
    s = fmaf(v.x, w[(k4 * 4 + 0) * 16 + c], s);
    s = fmaf(v.y, w[(k4 * 4 + 1) * 16 + c], s);
    s = fmaf(v.z, w[(k4 * 4 + 2) * 16 + c], s);
    s = fmaf(v.w, w[(k4 * 4 + 3) * 16 + c], s);
  }
  float4 mine = *(const float4*)(xr + c * 4);
  ushort ob[4] = {f2bf(mine.x), f2bf(mine.y), f2bf(mine.z), f2bf(mine.w)};
  *(ushort4*)(xbf + (size_t)n * 64 + c * 4) = *(const ushort4*)ob;
  al[idx] = s;
}

// ---------------- FUSED softmax weights + aggregation (R11 optimum: barrier-free) ----------------
// 4 waves/block, wave per node, waves fully independent: ws staging is wave-private,
// cross-lane visibility within a wave needs only in-order DS + lgkmcnt (compiler-
// inserted). wave_barrier() = compile-time reorder fence only.
// NOTE (R9/R12/R13): any +VGPR structural addition (prefetch, grid-stride loop)
// regressed via occupancy loss. VGPR 40 / ~46% occ is the verified optimum.
__global__ __launch_bounds__(256) void wagg_kernel(const ushort* __restrict__ xb,
                                                   const float* __restrict__ al,
                                                   const int* __restrict__ row_off,
                                                   const int* __restrict__ csr_src,
                                                   ushort* __restrict__ aggx){
  __shared__ float ws[4][64][8];   // 8 KB, wave-private slices
  const int wave = threadIdx.x >> 6, lane = threadIdx.x & 63;
  const int n = blockIdx.x * 4 + wave;
  const int s0 = row_off[n], s1 = row_off[n + 1];
  const int deg = s1 - s0;

  const int eo = lane >> 3, h = lane & 7;
  const float ald = al[n * 16 + 8 + h];

  // one load covers this node's first 64 src indices
  int idxv = (s0 + lane < s1) ? csr_src[s0 + lane] : 0;

  const bool fast = (deg <= 64);
  float wv[8];
  float sum = 0.f;
  if (fast){
#pragma unroll
    for (int i = 0; i < 8; ++i){
      int ee = eo + i * 8;
      int s = __shfl(idxv, ee, 64);
      float v = 0.f;
      if (ee < deg) v = __expf(lrelu(al[s * 16 + h] + ald));
      wv[i] = v; sum += v;
    }
  } else {
    for (int e = s0 + eo; e < s1; e += 8){
      int s = csr_src[e];
      sum += __expf(lrelu(al[s * 16 + h] + ald));
    }
  }
#pragma unroll
  for (int off = 8; off < 64; off <<= 1) sum += __shfl_xor(sum, off, 64);
  const float inv = 1.f / (sum + 1e-16f);

  float acc[8];
#pragma unroll
  for (int i = 0; i < 8; ++i) acc[i] = 0.f;

  const int nchunk = (deg + 63) >> 6;   // per-wave: no cross-wave coupling
  for (int c = 0; c < nchunk; ++c){
    const int base = s0 + c * 64;
    // phase 1: stage normalized weights (f32) for this chunk (wave-private)
    if (fast){
      if (c == 0){
#pragma unroll
        for (int i = 0; i < 8; ++i){
          int ee = eo + i * 8;
          if (ee < deg) ws[wave][ee][h] = wv[i] * inv;
        }
      }
    } else {
#pragma unroll
      for (int i = 0; i < 8; ++i){
        int e = base + eo + i * 8;
        if (e < s1){
          int s = csr_src[e];
          ws[wave][e - base][h] = __expf(lrelu(al[s * 16 + h] + ald)) * inv;
        }
      }
    }
    __builtin_amdgcn_wave_barrier();   // no reorder of reads above writes
    // phase 2: aggregate this chunk (lane = dim)
    const int cend = min(base + 64, s1);
    int e = base;
    for (; e + 4 <= cend; e += 4){
      int r0 = e - base;
      int sa, sb, sc, sd;
      if (fast){
        sa = __shfl(idxv, e - s0, 64);
        sb = __shfl(idxv, e - s0 + 1, 64);
        sc = __shfl(idxv, e - s0 + 2, 64);
        sd = __shfl(idxv, e - s0 + 3, 64);
      } else {
        sa = csr_src[e]; sb = csr_src[e + 1]; sc = csr_src[e + 2]; sd = csr_src[e + 3];
      }
      float xa = bf2f(xb[(size_t)sa * 64 + lane]);
      float xc = bf2f(xb[(size_t)sb * 64 + lane]);
      float xe = bf2f(xb[(size_t)sc * 64 + lane]);
      float xg = bf2f(xb[(size_t)sd * 64 + lane]);
      float4 wa0 = *(const float4*)&ws[wave][r0][0];
      float4 wa1 = *(const float4*)&ws[wave][r0][4];
      float4 wb0 = *(const float4*)&ws[wave][r0 + 1][0];
      float4 wb1 = *(const float4*)&ws[wave][r0 + 1][4];
      float4 wc0 = *(const float4*)&ws[wave][r0 + 2][0];
      float4 wc1 = *(const float4*)&ws[wave][r0 + 2][4];
      float4 wd0 = *(const float4*)&ws[wave][r0 + 3][0];
      float4 wd1 = *(const float4*)&ws[wave][r0 + 3][4];
      acc[0] = fmaf(wa0.x, xa, acc[0]); acc[1] = fmaf(wa0.y, xa, acc[1]);
      acc[2] = fmaf(wa0.z, xa, acc[2]); acc[3] = fmaf(wa0.w, xa, acc[3]);
      acc[4] = fmaf(wa1.x, xa, acc[4]); acc[5] = fmaf(wa1.y, xa, acc[5]);
      acc[6] = fmaf(wa1.z, xa, acc[6]); acc[7] = fmaf(wa1.w, xa, acc[7]);
      acc[0] = fmaf(wb0.x, xc, acc[0]); acc[1] = fmaf(wb0.y, xc, acc[1]);
      acc[2] = fmaf(wb0.z, xc, acc[2]); acc[3] = fmaf(wb0.w, xc, acc[3]);
      acc[4] = fmaf(wb1.x, xc, acc[4]); acc[5] = fmaf(wb1.y, xc, acc[5]);
      acc[6] = fmaf(wb1.z, xc, acc[6]); acc[7] = fmaf(wb1.w, xc, acc[7]);
      acc[0] = fmaf(wc0.x, xe, acc[0]); acc[1] = fmaf(wc0.y, xe, acc[1]);
      acc[2] = fmaf(wc0.z, xe, acc[2]); acc[3] = fmaf(wc0.w, xe, acc[3]);
      acc[4] = fmaf(wc1.x, xe, acc[4]); acc[5] = fmaf(wc1.y, xe, acc[5]);
      acc[6] = fmaf(wc1.z, xe, acc[6]); acc[7] = fmaf(wc1.w, xe, acc[7]);
      acc[0] = fmaf(wd0.x, xg, acc[0]); acc[1] = fmaf(wd0.y, xg, acc[1]);
      acc[2] = fmaf(wd0.z, xg, acc[2]); acc[3] = fmaf(wd0.w, xg, acc[3]);
      acc[4] = fmaf(wd1.x, xg, acc[4]); acc[5] = fmaf(wd1.y, xg, acc[5]);
      acc[6] = fmaf(wd1.z, xg, acc[6]); acc[7] = fmaf(wd1.w, xg, acc[7]);
    }
    for (; e < cend; ++e){
      int r0 = e - base;
      int sa = fast ? __shfl(idxv, e - s0, 64) : csr_src[e];
      float xa = bf2f(xb[(size_t)sa * 64 + lane]);
      float4 wa0 = *(const float4*)&ws[wave][r0][0];
      float4 wa1 = *(const float4*)&ws[wave][r0][4];
      acc[0] = fmaf(wa0.x, xa, acc[0]); acc[1] = fmaf(wa0.y, xa, acc[1]);
      acc[2] = fmaf(wa0.z, xa, acc[2]); acc[3] = fmaf(wa0.w, xa, acc[3]);
      acc[4] = fmaf(wa1.x, xa, acc[4]); acc[5] = fmaf(wa1.y, xa, acc[5]);
      acc[6] = fmaf(wa1.z, xa, acc[6]); acc[7] = fmaf(wa1.w, xa, acc[7]);
    }
    __builtin_amdgcn_wave_barrier();   // WAR fence before next chunk's restage
  }
  // packed store: k-order d*8+h, lane=d owns 8 consecutive bf16 = 16B
  uint o[4];
#pragma unroll
  for (int i = 0; i < 4; ++i)
    o[i] = (uint)f2bf(acc[2 * i]) | ((uint)f2bf(acc[2 * i + 1]) << 16);
  *(uint4*)(aggx + (size_t)n * 512 + lane * 8) = make_uint4(o[0], o[1], o[2], o[3]);
}

// ---------------- Y = aggx(bf16) @ W'(bf16) + bias + res(bf16) via MFMA; fused LN stats ----------------
__global__ __launch_bounds__(256) void outgemm_stats_kernel(const ushort* __restrict__ A,
                                                            const ushort* __restrict__ BT,
                                                            const float* __restrict__ bias,
                                                            const ushort* __restrict__ res,
                                                            const int* __restrict__ batch,
                                                            float* __restrict__ Y,
                                                            float* __restrict__ gs,
                                                            float* __restrict__ gss){
  __shared__ ushort Al[64][136];  // +8 pad
  __shared__ ushort Bl[64][136];
  __shared__ float gsl[NG], gssl[NG];
  const int t = threadIdx.x;
  const int wave = t >> 6, lane = t & 63;
  const int rowbase = blockIdx.x * 64;
  const int frow = lane & 15, kc = lane >> 4;
  if (t < NG){ gsl[t] = 0.f; gssl[t] = 0.f; }
  f32x4 acc[4];
#pragma unroll
  for (int ct = 0; ct < 4; ++ct) acc[ct] = (f32x4){0.f, 0.f, 0.f, 0.f};

  for (int k0 = 0; k0 < 512; k0 += 128){
#pragma unroll
    for (int ppass = 0; ppass < 4; ++ppass){
      int idx = (ppass * 256 + t) * 8;
      int r = idx >> 7, k = idx & 127;
      int grow = rowbase + r;
      uint4 v = make_uint4(0u, 0u, 0u, 0u);
      if (grow < N_NODES) v = *(const uint4*)(A + (size_t)grow * 512 + k0 + k);
      *(uint4*)&Al[r][k] = v;
      uint4 w = *(const uint4*)(BT + (size_t)r * 512 + k0 + k);
      *(uint4*)&Bl[r][k] = w;
    }
    __syncthreads();
#pragma unroll
    for (int kf = 0; kf < 4; ++kf){
      bf16x8 a = *(const bf16x8*)&Al[wave * 16 + frow][kf * 32 + kc * 8];
#pragma unroll
      for (int ct = 0; ct < 4; ++ct){
        bf16x8 b = *(const bf16x8*)&Bl[ct * 16 + frow][kf * 32 + kc * 8];
        acc[ct] = __builtin_amdgcn_mfma_f32_16x16x32_bf16(a, b, acc[ct], 0, 0, 0);
      }
    }
    __syncthreads();
  }
  const int col0 = lane & 15, rsub = (lane >> 4) * 4;
  float rs[4] = {0.f, 0.f, 0.f, 0.f}, rss[4] = {0.f, 0.f, 0.f, 0.f};
#pragma unroll
  for (int ct = 0; ct < 4; ++ct){
    int col = ct * 16 + col0;
    float bs = bias[col];
#pragma unroll
    for (int j = 0; j < 4; ++j){
      int grow = rowbase + wave * 16 + rsub + j;
      if (grow < N_NODES){
        float y = acc[ct][j] + bs + bf2f(res[(size_t)grow * 64 + col]);
        Y[(size_t)grow * 64 + col] = y;
        rs[j] += y;
        rss[j] = fmaf(y, y, rss[j]);
      }
    }
  }
#pragma unroll
  for (int j = 0; j < 4; ++j){
#pragma unroll
    for (int off = 1; off < 16; off <<= 1){
      rs[j] += __shfl_xor(rs[j], off, 64);
      rss[j] += __shfl_xor(rss[j], off, 64);
    }
  }
  if (col0 == 0){
#pragma unroll
    for (int j = 0; j < 4; ++j){
      int grow = rowbase + wave * 16 + rsub + j;
      if (grow < N_NODES){
        int g = batch[grow];
        atomicAdd(&gsl[g], rs[j]);
        atomicAdd(&gssl[g], rss[j]);
      }
    }
  }
  __syncthreads();
  if (t < NG && (gsl[t] != 0.f || gssl[t] != 0.f)){
    atomicAdd(&gs[t], gsl[t]);
    atomicAdd(&gss[t], gssl[t]);
  }
}

// ---------------- layer1 normalize+relu + layer2 al, fused (bf16 output only) ----------------
__global__ __launch_bounds__(256) void norm_relu_al_kernel(const float* __restrict__ Y,
                                                           const int* __restrict__ batch,
                                                           const int* __restrict__ gstart,
                                                           const float* __restrict__ gs,
                                                           const float* __restrict__ gss,
                                                           const float* __restrict__ lw,
                                                           const float* __restrict__ lb,
                                                           const float* __restrict__ wa,
                                                           ushort* __restrict__ outb,
                                                           float* __restrict__ al){
  __shared__ float rows[4][64];
  const int t = threadIdx.x;
  const int nl = t >> 6, c = t & 63;
  const int n = blockIdx.x * 4 + nl;
  int g = batch[n];
  float cnt = (float)(gstart[g + 1] - gstart[g]);
  float norm = fmaxf(cnt, 1.f) * 64.f;
  float m = gs[g] / norm;
  float var = fmaxf(gss[g] / norm - m * m, 0.f);
  float rstd = rsqrtf(var + 1e-5f);
  float v = (Y[(size_t)n * 64 + c] - m) * rstd * lw[c] + lb[c];
  float r = fmaxf(v, 0.f);
  outb[(size_t)n * 64 + c] = f2bf(r);
  rows[nl][c] = r;
  __syncthreads();
  if (t < 64){
    int nn = t >> 4, cc = t & 15;
    float s = 0.f;
#pragma unroll
    for (int k = 0; k < 64; ++k) s = fmaf(rows[nn][k], wa[k * 16 + cc], s);
    al[(size_t)(blockIdx.x * 4 + nn) * 16 + cc] = s;
  }
}

// ---------------- normalize + relu + pooled accumulation (layer 2); inline finalize ----------------
__global__ void norm_relu_pool_kernel(const float* __restrict__ Y, const int* __restrict__ batch,
                                      const int* __restrict__ gstart, const float* __restrict__ gs,
                                      const float* __restrict__ gss,
                                      const float* __restrict__ lw, const float* __restrict__ lb,
                                      float* __restrict__ pooled){
  int w = (int)((blockIdx.x * blockDim.x + threadIdx.x) >> 6);
  int lane = threadIdx.x & 63;
  int nbase = w * 16;
  if (nbase >= N_NODES) return;
  int nend = min(nbase + 16, N_NODES);
  float accv = 0.f;
  int g = batch[nbase];
  float cnt = (float)(gstart[g + 1] - gstart[g]);
  float norm = fmaxf(cnt, 1.f) * 64.f;
  float m = gs[g] / norm;
  float var = fmaxf(gss[g] / norm - m * m, 0.f);
  float rstd = rsqrtf(var + 1e-5f);
  for (int n = nbase; n < nend; ++n){
    int gn = batch[n];
    if (gn != g){
      atomicAdd(&pooled[g * 64 + lane], accv);
      accv = 0.f; g = gn;
      cnt = (float)(gstart[g + 1] - gstart[g]);
      norm = fmaxf(cnt, 1.f) * 64.f;
      m = gs[g] / norm;
      var = fmaxf(gss[g] / norm - m * m, 0.f);
      rstd = rsqrtf(var + 1e-5f);
    }
    float v = (Y[(size_t)n * 64 + lane] - m) * rstd * lw[lane] + lb[lane];
    accv += fmaxf(v, 0.f);
  }
  atomicAdd(&pooled[g * 64 + lane], accv);
}

// ---------------- head ----------------
__global__ void head_kernel(const float* __restrict__ pooled, const int* __restrict__ gstart,
                            const float* __restrict__ Wh, const float* __restrict__ bh,
                            float* __restrict__ out){
  int idx = blockIdx.x * blockDim.x + threadIdx.x;
  if (idx >= NG * 32) return;
  int g = idx >> 5, o = idx & 31;
  float cnt = (float)(gstart[g + 1] - gstart[g]);
  float inv = 1.f / fmaxf(cnt, 1.f);
  float s = 0.f;
#pragma unroll
  for (int d = 0; d < 64; ++d) s = fmaf(pooled[g * 64 + d] * inv, Wh[d * 32 + o], s);
  out[idx] = fmaxf(s + bh[o], 0.f);
}

// ---------------- launch ----------------
extern "C" void kernel_launch(void* const* d_in, const int* in_sizes, int n_in,
                              void* d_out, int out_size, void* d_ws, size_t ws_size,
                              hipStream_t stream){
  const float* x     = (const float*)d_in[0];
  const int*   ei    = (const int*)d_in[1];
  const int*   batch = (const int*)d_in[2];
  const float* W1    = (const float*)d_in[3];
  const float* as1   = (const float*)d_in[4];
  const float* ad1   = (const float*)d_in[5];
  const float* b1    = (const float*)d_in[6];
  const float* l1w   = (const float*)d_in[7];
  const float* l1b   = (const float*)d_in[8];
  const float* W2    = (const float*)d_in[9];
  const float* as2   = (const float*)d_in[10];
  const float* ad2   = (const float*)d_in[11];
  const float* b2    = (const float*)d_in[12];
  const float* l2w   = (const float*)d_in[13];
  const float* l2b   = (const float*)d_in[14];
  const float* Wh    = (const float*)d_in[15];
  const float* bh    = (const float*)d_in[16];
  float* out = (float*)d_out;

  char* p = (char*)d_ws;
  auto alloc = [&](size_t bytes) -> void* {
    void* r = (void*)p;
    p += (bytes + 255) & ~(size_t)255;
    return r;
  };
  int*    counts   = (int*)alloc(N_NODES * 4);
  int*    cursor   = (int*)alloc(N_NODES * 4);   // adjacent to counts: one memset
  int*    row_off  = (int*)alloc((N_NODES + 1) * 4);
  int*    csr_src  = (int*)alloc(E_TOT * 4);
  int*    gstart   = (int*)alloc((NG + 1) * 4);
  int*    blocksum = (int*)alloc((SCAN_NB + 1) * 4);
  int*    blockoff = (int*)alloc((SCAN_NB + 1) * 4);
  float*  wa1      = (float*)alloc(64 * 16 * 4);
  float*  wa2      = (float*)alloc(64 * 16 * 4);
  ushort* w1pT     = (ushort*)alloc(64 * 512 * 2);
  ushort* w2pT     = (ushort*)alloc(64 * 512 * 2);
  float*  al       = (float*)alloc((size_t)N_NODES * 16 * 4);
  ushort* xbf      = (ushort*)alloc((size_t)N_NODES * 64 * 2);
  ushort* y1b      = (ushort*)alloc((size_t)N_NODES * 64 * 2);
  ushort* aggx     = (ushort*)alloc((size_t)N_NODES * 512 * 2);
  float*  y1p      = (float*)alloc((size_t)N_NODES * 64 * 4);
  float*  y2p      = y1p;  // y1p dead after layer-1 norm_relu_al
  float*  gstats   = (float*)alloc(8 * NG * 4);
  float*  pooled   = (float*)alloc(NG * 64 * 4);  // adjacent to gstats: one memset
  float* gs1 = gstats, *gss1 = gstats + NG, *gs2 = gstats + 2*NG, *gss2 = gstats + 3*NG;

  hipMemsetAsync(counts, 0, (size_t)((char*)row_off - (char*)counts), stream);
  hipMemsetAsync(gstats, 0, (size_t)((char*)pooled - (char*)gstats) + NG * 64 * 4, stream);

  // setup: prep + bounds + count in one kernel
  setup_kernel<<<(SETUP_TOTAL + 255) / 256, 256, 0, stream>>>(
      W1, as1, ad1, W2, as2, ad2, batch, ei, wa1, wa2, w1pT, w2pT, gstart, counts);

  // CSR scan + scatter
  scan1_kernel<<<SCAN_NB, SCAN_B, 0, stream>>>(counts, row_off, blocksum);
  scan2_kernel<<<1, 64, 0, stream>>>(blocksum, blockoff);
  scan3_kernel<<<(N_NODES + 255) / 256, 256, 0, stream>>>(row_off, blockoff);
  scatter_kernel<<<(E_TOT + 255) / 256, 256, 0, stream>>>(ei, row_off, cursor, csr_src);

  const int waggBlocks = N_NODES / 4;   // exactly 12500
  const int waveBlocks = ((N_NODES + 15) / 16 * 64 + 255) / 256;
  const int gemmBlocks = (N_NODES + 63) / 64;

  // ---- layer 1 ----
  al1_kernel<<<(N_NODES * 16 + 255) / 256, 256, 0, stream>>>(x, wa1, al, xbf);
  wagg_kernel<<<waggBlocks, 256, 0, stream>>>(xbf, al, row_off, csr_src, aggx);
  outgemm_stats_kernel<<<gemmBlocks, 256, 0, stream>>>(aggx, w1pT, b1, xbf, batch, y1p, gs1, gss1);
  norm_relu_al_kernel<<<waggBlocks, 256, 0, stream>>>(y1p, batch, gstart, gs1, gss1, l1w, l1b, wa2, y1b, al);

  // ---- layer 2 ----
  wagg_kernel<<<waggBlocks, 256, 0, stream>>>(y1b, al, row_off, csr_src, aggx);
  outgemm_stats_kernel<<<gemmBlocks, 256, 0, stream>>>(aggx, w2pT, b2, y1b, batch, y2p, gs2, gss2);
  norm_relu_pool_kernel<<<waveBlocks, 256, 0, stream>>>(y2p, batch, gstart, gs2, gss2, l2w, l2b, pooled);

  // ---- head ----
  head_kernel<<<(NG * 32 + 255) / 256, 256, 0, stream>>>(pooled, gstart, Wh, bh, out);
}

// Round 15
// 211.733 us; speedup vs baseline: 1.2664x; 1.0560x over previous
//
#include <hip/hip_runtime.h>
#include <math.h>

#define N_NODES 50000
#define N_EDGES 400000
#define E_TOT   (N_EDGES + N_NODES)
#define NG      64
#define NEG_SLOPE 0.2f

typedef __attribute__((ext_vector_type(8))) short bf16x8;
typedef __attribute__((ext_vector_type(4))) float f32x4;

// ---------------- helpers ----------------
__device__ __forceinline__ float lrelu(float x){ return x > 0.f ? x : NEG_SLOPE * x; }
__device__ __forceinline__ ushort f2bf(float f){
  union { float f; unsigned u; } v; v.f = f;
  unsigned r = v.u + 0x7FFFu + ((v.u >> 16) & 1u);  // RNE
  return (ushort)(r >> 16);
}
__device__ __forceinline__ float bf2f(ushort u){
  return __uint_as_float(((unsigned)u) << 16);
}

// ---------------- setup: prep weights + graph bounds + edge count, ONE kernel ----------------
#define SETUP_PREP   (2048 + 2 * 32768)
#define SETUP_BOUNDS (SETUP_PREP + N_NODES + 1)
#define SETUP_TOTAL  (SETUP_BOUNDS + E_TOT)

__global__ void setup_kernel(const float* __restrict__ W1, const float* __restrict__ as1,
                             const float* __restrict__ ad1, const float* __restrict__ W2,
                             const float* __restrict__ as2, const float* __restrict__ ad2,
                             const int* __restrict__ batch, const int* __restrict__ ei,
                             float* __restrict__ wa1, float* __restrict__ wa2,
                             ushort* __restrict__ w1pT, ushort* __restrict__ w2pT,
                             int* __restrict__ gstart, int* __restrict__ counts){
  int idx = blockIdx.x * blockDim.x + threadIdx.x;
  if (idx < 2048){
    const float* W = (idx < 1024) ? W1 : W2;
    const float* asr = (idx < 1024) ? as1 : as2;
    const float* adr = (idx < 1024) ? ad1 : ad2;
    float* wa = (idx < 1024) ? wa1 : wa2;
    int i = idx & 1023;
    int k = i >> 4, c = i & 15;
    int h = c & 7;
    const float* a = (c < 8) ? asr : adr;
    float s = 0.f;
#pragma unroll
    for (int d = 0; d < 64; ++d) s = fmaf(W[k * 512 + h * 64 + d], a[h * 64 + d], s);
    wa[i] = s;
  } else if (idx < SETUP_PREP){
    int i = idx - 2048;
    const float* W = (i < 32768) ? W1 : W2;
    ushort* wpT = (i < 32768) ? w1pT : w2pT;
    i &= 32767;
    // k-order = d*8 + h (matches wagg's packed store)
    int j = i >> 9, k = i & 511;
    int d = k >> 3, h = k & 7;
    wpT[i] = f2bf(W[d * 512 + h * 64 + j] * 0.125f);
  } else if (idx < SETUP_BOUNDS){
    int n = idx - SETUP_PREP;
    int g = (n < N_NODES) ? batch[n] : NG;
    if (n == 0){
      for (int gg = 0; gg <= g; ++gg) gstart[gg] = 0;
    } else {
      int gp = batch[n - 1];
      for (int gg = gp + 1; gg <= g; ++gg) gstart[gg] = n;
    }
  } else if (idx < SETUP_TOTAL){
    int e = idx - SETUP_BOUNDS;
    int dst = (e < N_EDGES) ? ei[N_EDGES + e] : (e - N_EDGES);
    atomicAdd(&counts[dst], 1);
  }
}

// ---------- two-level exclusive scan of counts[N_NODES] -> row_off ----------
#define SCAN_B 1024
#define SCAN_NB ((N_NODES + SCAN_B - 1) / SCAN_B)   // 49

__global__ __launch_bounds__(SCAN_B) void scan1_kernel(const int* __restrict__ counts,
                                                       int* __restrict__ row_off,
                                                       int* __restrict__ blocksum){
  __shared__ int sh[SCAN_B];
  int i = blockIdx.x * SCAN_B + threadIdx.x;
  int v = (i < N_NODES) ? counts[i] : 0;
  sh[threadIdx.x] = v;
  __syncthreads();
#pragma unroll
  for (int off = 1; off < SCAN_B; off <<= 1){
    int add = (threadIdx.x >= (unsigned)off) ? sh[threadIdx.x - off] : 0;
    __syncthreads();
    sh[threadIdx.x] += add;
    __syncthreads();
  }
  if (i < N_NODES) row_off[i] = sh[threadIdx.x] - v;
  if (threadIdx.x == SCAN_B - 1) blocksum[blockIdx.x] = sh[SCAN_B - 1];
}

__global__ void scan2_kernel(int* __restrict__ blocksum, int* __restrict__ blockoff){
  __shared__ int sh[64];
  int t = threadIdx.x;
  int v = (t < SCAN_NB) ? blocksum[t] : 0;
  sh[t] = v;
  __syncthreads();
#pragma unroll
  for (int off = 1; off < 64; off <<= 1){
    int add = (t >= off) ? sh[t - off] : 0;
    __syncthreads();
    sh[t] += add;
    __syncthreads();
  }
  if (t < SCAN_NB) blockoff[t] = sh[t] - v;
  if (t == 63) blockoff[SCAN_NB] = sh[63];
}

__global__ void scan3_kernel(int* __restrict__ row_off, const int* __restrict__ blockoff){
  int i = blockIdx.x * blockDim.x + threadIdx.x;
  if (i < N_NODES) row_off[i] += blockoff[i >> 10];
  if (i == 0) row_off[N_NODES] = blockoff[SCAN_NB];
}

__global__ void scatter_kernel(const int* __restrict__ ei, const int* __restrict__ row_off,
                               int* __restrict__ cursor, int* __restrict__ csr_src){
  int e = blockIdx.x * blockDim.x + threadIdx.x;
  if (e >= E_TOT) return;
  int src, dst;
  if (e < N_EDGES){ src = ei[e]; dst = ei[N_EDGES + e]; }
  else            { src = dst = e - N_EDGES; }
  int pos = row_off[dst] + atomicAdd(&cursor[dst], 1);
  csr_src[pos] = src;
}

// ---------------- layer1 al from f32 x; also emits x as bf16 ----------------
__global__ void al1_kernel(const float* __restrict__ xin, const float* __restrict__ wa,
                           float* __restrict__ al, ushort* __restrict__ xbf){
  __shared__ float w[64 * 16];
  for (int i = threadIdx.x; i < 1024; i += blockDim.x) w[i] = wa[i];
  __syncthreads();
  int idx = blockIdx.x * blockDim.x + threadIdx.x;
  if (idx >= N_NODES * 16) return;
  int n = idx >> 4, c = idx & 15;
  const float* xr = xin + (size_t)n * 64;
  float s = 0.f;
#pragma unroll
  for (int k4 = 0; k4 < 16; ++k4){
    float4 v = *(const float4*)(xr + k4 * 4);
    s = fmaf(v.x, w[(k4 * 4 + 0) * 16 + c], s);
    s = fmaf(v.y, w[(k4 * 4 + 1) * 16 + c], s);
    s = fmaf(v.z, w[(k4 * 4 + 2) * 16 + c], s);
    s = fmaf(v.w, w[(k4 * 4 + 3) * 16 + c], s);
  }
  float4 mine = *(const float4*)(xr + c * 4);
  ushort ob[4] = {f2bf(mine.x), f2bf(mine.y), f2bf(mine.z), f2bf(mine.w)};
  *(ushort4*)(xbf + (size_t)n * 64 + c * 4) = *(const ushort4*)ob;
  al[idx] = s;
}

// ---------------- FUSED softmax weights + aggregation (v7: dynamic softmax bound) ----------------
// R11 structure (barrier-free, wave-private LDS) with one change: the fast-path
// exp/stage loop runs ceil(deg/8) iterations (wave-uniform bound) instead of a
// fully-unrolled 8 with exec-masked dead iterations. deg<=16 for ~95% of nodes
// -> ~6 dead iterations of shfl/cmp/exp skipped per node.
// NOTE (R9/R12/R13): +VGPR structural additions regress via occupancy loss.
__global__ __launch_bounds__(256) void wagg_kernel(const ushort* __restrict__ xb,
                                                   const float* __restrict__ al,
                                                   const int* __restrict__ row_off,
                                                   const int* __restrict__ csr_src,
                                                   ushort* __restrict__ aggx){
  __shared__ float ws[4][64][8];   // 8 KB, wave-private slices (unnormalized w)
  __shared__ float sinv[4][8];
  const int wave = threadIdx.x >> 6, lane = threadIdx.x & 63;
  const int n = blockIdx.x * 4 + wave;
  const int s0 = row_off[n], s1 = row_off[n + 1];
  const int deg = s1 - s0;

  const int eo = lane >> 3, h = lane & 7;
  const float ald = al[n * 16 + 8 + h];

  // one load covers this node's first 64 src indices
  int idxv = (s0 + lane < s1) ? csr_src[s0 + lane] : 0;

  const bool fast = (deg <= 64);
  float sum = 0.f;
  if (fast){
    // ceil(deg/8) iterations only (wave-uniform bound); stage unnormalized w
    const int imax = (deg + 7) >> 3;
#pragma unroll 1
    for (int i = 0; i < imax; ++i){
      int ee = eo + i * 8;
      int s = __shfl(idxv, ee, 64);
      float v = 0.f;
      if (ee < deg) v = __expf(lrelu(al[s * 16 + h] + ald));
      ws[wave][ee][h] = v;   // ee < 64 always (deg<=64); zero-pads partial tail
      sum += v;
    }
    // zero any slots beyond imax*8 that phase 2 could touch in the 4-unroll:
    // phase 2 only reads e < cend <= deg, and slots [deg, imax*8) were zeroed
    // above, so no extra clearing is needed.
  } else {
    for (int e = s0 + eo; e < s1; e += 8){
      int s = csr_src[e];
      sum += __expf(lrelu(al[s * 16 + h] + ald));
    }
  }
#pragma unroll
  for (int off = 8; off < 64; off <<= 1) sum += __shfl_xor(sum, off, 64);
  if (eo == 0) sinv[wave][h] = 1.f / (sum + 1e-16f);

  float acc[8];
#pragma unroll
  for (int i = 0; i < 8; ++i) acc[i] = 0.f;

  const int nchunk = (deg + 63) >> 6;   // per-wave: no cross-wave coupling
  for (int c = 0; c < nchunk; ++c){
    const int base = s0 + c * 64;
    if (!fast){
      // generic staging for this chunk (unnormalized)
#pragma unroll
      for (int i = 0; i < 8; ++i){
        int e = base + eo + i * 8;
        if (e < s1){
          int s = csr_src[e];
          ws[wave][e - base][h] = __expf(lrelu(al[s * 16 + h] + ald));
        }
      }
    }
    __builtin_amdgcn_wave_barrier();   // no reorder of reads above writes
    // phase 2: aggregate this chunk (lane = dim)
    const int cend = min(base + 64, s1);
    int e = base;
    for (; e + 4 <= cend; e += 4){
      int r0 = e - base;
      int sa, sb, sc, sd;
      if (fast){
        sa = __shfl(idxv, e - s0, 64);
        sb = __shfl(idxv, e - s0 + 1, 64);
        sc = __shfl(idxv, e - s0 + 2, 64);
        sd = __shfl(idxv, e - s0 + 3, 64);
      } else {
        sa = csr_src[e]; sb = csr_src[e + 1]; sc = csr_src[e + 2]; sd = csr_src[e + 3];
      }
      float xa = bf2f(xb[(size_t)sa * 64 + lane]);
      float xc = bf2f(xb[(size_t)sb * 64 + lane]);
      float xe = bf2f(xb[(size_t)sc * 64 + lane]);
      float xg = bf2f(xb[(size_t)sd * 64 + lane]);
      float4 wa0 = *(const float4*)&ws[wave][r0][0];
      float4 wa1 = *(const float4*)&ws[wave][r0][4];
      float4 wb0 = *(const float4*)&ws[wave][r0 + 1][0];
      float4 wb1 = *(const float4*)&ws[wave][r0 + 1][4];
      float4 wc0 = *(const float4*)&ws[wave][r0 + 2][0];
      float4 wc1 = *(const float4*)&ws[wave][r0 + 2][4];
      float4 wd0 = *(const float4*)&ws[wave][r0 + 3][0];
      float4 wd1 = *(const float4*)&ws[wave][r0 + 3][4];
      acc[0] = fmaf(wa0.x, xa, acc[0]); acc[1] = fmaf(wa0.y, xa, acc[1]);
      acc[2] = fmaf(wa0.z, xa, acc[2]); acc[3] = fmaf(wa0.w, xa, acc[3]);
      acc[4] = fmaf(wa1.x, xa, acc[4]); acc[5] = fmaf(wa1.y, xa, acc[5]);
      acc[6] = fmaf(wa1.z, xa, acc[6]); acc[7] = fmaf(wa1.w, xa, acc[7]);
      acc[0] = fmaf(wb0.x, xc, acc[0]); acc[1] = fmaf(wb0.y, xc, acc[1]);
      acc[2] = fmaf(wb0.z, xc, acc[2]); acc[3] = fmaf(wb0.w, xc, acc[3]);
      acc[4] = fmaf(wb1.x, xc, acc[4]); acc[5] = fmaf(wb1.y, xc, acc[5]);
      acc[6] = fmaf(wb1.z, xc, acc[6]); acc[7] = fmaf(wb1.w, xc, acc[7]);
      acc[0] = fmaf(wc0.x, xe, acc[0]); acc[1] = fmaf(wc0.y, xe, acc[1]);
      acc[2] = fmaf(wc0.z, xe, acc[2]); acc[3] = fmaf(wc0.w, xe, acc[3]);
      acc[4] = fmaf(wc1.x, xe, acc[4]); acc[5] = fmaf(wc1.y, xe, acc[5]);
      acc[6] = fmaf(wc1.z, xe, acc[6]); acc[7] = fmaf(wc1.w, xe, acc[7]);
      acc[0] = fmaf(wd0.x, xg, acc[0]); acc[1] = fmaf(wd0.y, xg, acc[1]);
      acc[2] = fmaf(wd0.z, xg, acc[2]); acc[3] = fmaf(wd0.w, xg, acc[3]);
      acc[4] = fmaf(wd1.x, xg, acc[4]); acc[5] = fmaf(wd1.y, xg, acc[5]);
      acc[6] = fmaf(wd1.z, xg, acc[6]); acc[7] = fmaf(wd1.w, xg, acc[7]);
    }
    for (; e < cend; ++e){
      int r0 = e - base;
      int sa = fast ? __shfl(idxv, e - s0, 64) : csr_src[e];
      float xa = bf2f(xb[(size_t)sa * 64 + lane]);
      float4 wa0 = *(const float4*)&ws[wave][r0][0];
      float4 wa1 = *(const float4*)&ws[wave][r0][4];
      acc[0] = fmaf(wa0.x, xa, acc[0]); acc[1] = fmaf(wa0.y, xa, acc[1]);
      acc[2] = fmaf(wa0.z, xa, acc[2]); acc[3] = fmaf(wa0.w, xa, acc[3]);
      acc[4] = fmaf(wa1.x, xa, acc[4]); acc[5] = fmaf(wa1.y, xa, acc[5]);
      acc[6] = fmaf(wa1.z, xa, acc[6]); acc[7] = fmaf(wa1.w, xa, acc[7]);
    }
    __builtin_amdgcn_wave_barrier();   // WAR fence before next chunk's restage
  }
  // scale by 1/sum per head, pack, store (k-order d*8+h; lane = d)
  float4 i0 = *(const float4*)&sinv[wave][0];
  float4 i1 = *(const float4*)&sinv[wave][4];
  acc[0] *= i0.x; acc[1] *= i0.y; acc[2] *= i0.z; acc[3] *= i0.w;
  acc[4] *= i1.x; acc[5] *= i1.y; acc[6] *= i1.z; acc[7] *= i1.w;
  uint o[4];
#pragma unroll
  for (int i = 0; i < 4; ++i)
    o[i] = (uint)f2bf(acc[2 * i]) | ((uint)f2bf(acc[2 * i + 1]) << 16);
  *(uint4*)(aggx + (size_t)n * 512 + lane * 8) = make_uint4(o[0], o[1], o[2], o[3]);
}

// ---------------- Y = aggx(bf16) @ W'(bf16) + bias + res(bf16) via MFMA; fused LN stats ----------------
__global__ __launch_bounds__(256) void outgemm_stats_kernel(const ushort* __restrict__ A,
                                                            const ushort* __restrict__ BT,
                                                            const float* __restrict__ bias,
                                                            const ushort* __restrict__ res,
                                                            const int* __restrict__ batch,
                                                            float* __restrict__ Y,
                                                            float* __restrict__ gs,
                                                            float* __restrict__ gss){
  __shared__ ushort Al[64][136];  // +8 pad
  __shared__ ushort Bl[64][136];
  __shared__ float gsl[NG], gssl[NG];
  const int t = threadIdx.x;
  const int wave = t >> 6, lane = t & 63;
  const int rowbase = blockIdx.x * 64;
  const int frow = lane & 15, kc = lane >> 4;
  if (t < NG){ gsl[t] = 0.f; gssl[t] = 0.f; }
  f32x4 acc[4];
#pragma unroll
  for (int ct = 0; ct < 4; ++ct) acc[ct] = (f32x4){0.f, 0.f, 0.f, 0.f};

  for (int k0 = 0; k0 < 512; k0 += 128){
#pragma unroll
    for (int ppass = 0; ppass < 4; ++ppass){
      int idx = (ppass * 256 + t) * 8;
      int r = idx >> 7, k = idx & 127;
      int grow = rowbase + r;
      uint4 v = make_uint4(0u, 0u, 0u, 0u);
      if (grow < N_NODES) v = *(const uint4*)(A + (size_t)grow * 512 + k0 + k);
      *(uint4*)&Al[r][k] = v;
      uint4 w = *(const uint4*)(BT + (size_t)r * 512 + k0 + k);
      *(uint4*)&Bl[r][k] = w;
    }
    __syncthreads();
#pragma unroll
    for (int kf = 0; kf < 4; ++kf){
      bf16x8 a = *(const bf16x8*)&Al[wave * 16 + frow][kf * 32 + kc * 8];
#pragma unroll
      for (int ct = 0; ct < 4; ++ct){
        bf16x8 b = *(const bf16x8*)&Bl[ct * 16 + frow][kf * 32 + kc * 8];
        acc[ct] = __builtin_amdgcn_mfma_f32_16x16x32_bf16(a, b, acc[ct], 0, 0, 0);
      }
    }
    __syncthreads();
  }
  const int col0 = lane & 15, rsub = (lane >> 4) * 4;
  float rs[4] = {0.f, 0.f, 0.f, 0.f}, rss[4] = {0.f, 0.f, 0.f, 0.f};
#pragma unroll
  for (int ct = 0; ct < 4; ++ct){
    int col = ct * 16 + col0;
    float bs = bias[col];
#pragma unroll
    for (int j = 0; j < 4; ++j){
      int grow = rowbase + wave * 16 + rsub + j;
      if (grow < N_NODES){
        float y = acc[ct][j] + bs + bf2f(res[(size_t)grow * 64 + col]);
        Y[(size_t)grow * 64 + col] = y;
        rs[j] += y;
        rss[j] = fmaf(y, y, rss[j]);
      }
    }
  }
#pragma unroll
  for (int j = 0; j < 4; ++j){
#pragma unroll
    for (int off = 1; off < 16; off <<= 1){
      rs[j] += __shfl_xor(rs[j], off, 64);
      rss[j] += __shfl_xor(rss[j], off, 64);
    }
  }
  if (col0 == 0){
#pragma unroll
    for (int j = 0; j < 4; ++j){
      int grow = rowbase + wave * 16 + rsub + j;
      if (grow < N_NODES){
        int g = batch[grow];
        atomicAdd(&gsl[g], rs[j]);
        atomicAdd(&gssl[g], rss[j]);
      }
    }
  }
  __syncthreads();
  if (t < NG && (gsl[t] != 0.f || gssl[t] != 0.f)){
    atomicAdd(&gs[t], gsl[t]);
    atomicAdd(&gss[t], gssl[t]);
  }
}

// ---------------- layer1 normalize+relu + layer2 al, fused (bf16 output only) ----------------
__global__ __launch_bounds__(256) void norm_relu_al_kernel(const float* __restrict__ Y,
                                                           const int* __restrict__ batch,
                                                           const int* __restrict__ gstart,
                                                           const float* __restrict__ gs,
                                                           const float* __restrict__ gss,
                                                           const float* __restrict__ lw,
                                                           const float* __restrict__ lb,
                                                           const float* __restrict__ wa,
                                                           ushort* __restrict__ outb,
                                                           float* __restrict__ al){
  __shared__ float rows[4][64];
  const int t = threadIdx.x;
  const int nl = t >> 6, c = t & 63;
  const int n = blockIdx.x * 4 + nl;
  int g = batch[n];
  float cnt = (float)(gstart[g + 1] - gstart[g]);
  float norm = fmaxf(cnt, 1.f) * 64.f;
  float m = gs[g] / norm;
  float var = fmaxf(gss[g] / norm - m * m, 0.f);
  float rstd = rsqrtf(var + 1e-5f);
  float v = (Y[(size_t)n * 64 + c] - m) * rstd * lw[c] + lb[c];
  float r = fmaxf(v, 0.f);
  outb[(size_t)n * 64 + c] = f2bf(r);
  rows[nl][c] = r;
  __syncthreads();
  if (t < 64){
    int nn = t >> 4, cc = t & 15;
    float s = 0.f;
#pragma unroll
    for (int k = 0; k < 64; ++k) s = fmaf(rows[nn][k], wa[k * 16 + cc], s);
    al[(size_t)(blockIdx.x * 4 + nn) * 16 + cc] = s;
  }
}

// ---------------- normalize + relu + pooled accumulation (layer 2); inline finalize ----------------
__global__ void norm_relu_pool_kernel(const float* __restrict__ Y, const int* __restrict__ batch,
                                      const int* __restrict__ gstart, const float* __restrict__ gs,
                                      const float* __restrict__ gss,
                                      const float* __restrict__ lw, const float* __restrict__ lb,
                                      float* __restrict__ pooled){
  int w = (int)((blockIdx.x * blockDim.x + threadIdx.x) >> 6);
  int lane = threadIdx.x & 63;
  int nbase = w * 16;
  if (nbase >= N_NODES) return;
  int nend = min(nbase + 16, N_NODES);
  float accv = 0.f;
  int g = batch[nbase];
  float cnt = (float)(gstart[g + 1] - gstart[g]);
  float norm = fmaxf(cnt, 1.f) * 64.f;
  float m = gs[g] / norm;
  float var = fmaxf(gss[g] / norm - m * m, 0.f);
  float rstd = rsqrtf(var + 1e-5f);
  for (int n = nbase; n < nend; ++n){
    int gn = batch[n];
    if (gn != g){
      atomicAdd(&pooled[g * 64 + lane], accv);
      accv = 0.f; g = gn;
      cnt = (float)(gstart[g + 1] - gstart[g]);
      norm = fmaxf(cnt, 1.f) * 64.f;
      m = gs[g] / norm;
      var = fmaxf(gss[g] / norm - m * m, 0.f);
      rstd = rsqrtf(var + 1e-5f);
    }
    float v = (Y[(size_t)n * 64 + lane] - m) * rstd * lw[lane] + lb[lane];
    accv += fmaxf(v, 0.f);
  }
  atomicAdd(&pooled[g * 64 + lane], accv);
}

// ---------------- head ----------------
__global__ void head_kernel(const float* __restrict__ pooled, const int* __restrict__ gstart,
                            const float* __restrict__ Wh, const float* __restrict__ bh,
                            float* __restrict__ out){
  int idx = blockIdx.x * blockDim.x + threadIdx.x;
  if (idx >= NG * 32) return;
  int g = idx >> 5, o = idx & 31;
  float cnt = (float)(gstart[g + 1] - gstart[g]);
  float inv = 1.f / fmaxf(cnt, 1.f);
  float s = 0.f;
#pragma unroll
  for (int d = 0; d < 64; ++d) s = fmaf(pooled[g * 64 + d] * inv, Wh[d * 32 + o], s);
  out[idx] = fmaxf(s + bh[o], 0.f);
}

// ---------------- launch ----------------
extern "C" void kernel_launch(void* const* d_in, const int* in_sizes, int n_in,
                              void* d_out, int out_size, void* d_ws, size_t ws_size,
                              hipStream_t stream){
  const float* x     = (const float*)d_in[0];
  const int*   ei    = (const int*)d_in[1];
  const int*   batch = (const int*)d_in[2];
  const float* W1    = (const float*)d_in[3];
  const float* as1   = (const float*)d_in[4];
  const float* ad1   = (const float*)d_in[5];
  const float* b1    = (const float*)d_in[6];
  const float* l1w   = (const float*)d_in[7];
  const float* l1b   = (const float*)d_in[8];
  const float* W2    = (const float*)d_in[9];
  const float* as2   = (const float*)d_in[10];
  const float* ad2   = (const float*)d_in[11];
  const float* b2    = (const float*)d_in[12];
  const float* l2w   = (const float*)d_in[13];
  const float* l2b   = (const float*)d_in[14];
  const float* Wh    = (const float*)d_in[15];
  const float* bh    = (const float*)d_in[16];
  float* out = (float*)d_out;

  char* p = (char*)d_ws;
  auto alloc = [&](size_t bytes) -> void* {
    void* r = (void*)p;
    p += (bytes + 255) & ~(size_t)255;
    return r;
  };
  int*    counts   = (int*)alloc(N_NODES * 4);
  int*    cursor   = (int*)alloc(N_NODES * 4);   // adjacent to counts: one memset
  int*    row_off  = (int*)alloc((N_NODES + 1) * 4);
  int*    csr_src  = (int*)alloc(E_TOT * 4);
  int*    gstart   = (int*)alloc((NG + 1) * 4);
  int*    blocksum = (int*)alloc((SCAN_NB + 1) * 4);
  int*    blockoff = (int*)alloc((SCAN_NB + 1) * 4);
  float*  wa1      = (float*)alloc(64 * 16 * 4);
  float*  wa2      = (float*)alloc(64 * 16 * 4);
  ushort* w1pT     = (ushort*)alloc(64 * 512 * 2);
  ushort* w2pT     = (ushort*)alloc(64 * 512 * 2);
  float*  al       = (float*)alloc((size_t)N_NODES * 16 * 4);
  ushort* xbf      = (ushort*)alloc((size_t)N_NODES * 64 * 2);
  ushort* y1b      = (ushort*)alloc((size_t)N_NODES * 64 * 2);
  ushort* aggx     = (ushort*)alloc((size_t)N_NODES * 512 * 2);
  float*  y1p      = (float*)alloc((size_t)N_NODES * 64 * 4);
  float*  y2p      = y1p;  // y1p dead after layer-1 norm_relu_al
  float*  gstats   = (float*)alloc(8 * NG * 4);
  float*  pooled   = (float*)alloc(NG * 64 * 4);  // adjacent to gstats: one memset
  float* gs1 = gstats, *gss1 = gstats + NG, *gs2 = gstats + 2*NG, *gss2 = gstats + 3*NG;

  hipMemsetAsync(counts, 0, (size_t)((char*)row_off - (char*)counts), stream);
  hipMemsetAsync(gstats, 0, (size_t)((char*)pooled - (char*)gstats) + NG * 64 * 4, stream);

  // setup: prep + bounds + count in one kernel
  setup_kernel<<<(SETUP_TOTAL + 255) / 256, 256, 0, stream>>>(
      W1, as1, ad1, W2, as2, ad2, batch, ei, wa1, wa2, w1pT, w2pT, gstart, counts);

  // CSR scan + scatter
  scan1_kernel<<<SCAN_NB, SCAN_B, 0, stream>>>(counts, row_off, blocksum);
  scan2_kernel<<<1, 64, 0, stream>>>(blocksum, blockoff);
  scan3_kernel<<<(N_NODES + 255) / 256, 256, 0, stream>>>(row_off, blockoff);
  scatter_kernel<<<(E_TOT + 255) / 256, 256, 0, stream>>>(ei, row_off, cursor, csr_src);

  const int waggBlocks = N_NODES / 4;   // exactly 12500
  const int waveBlocks = ((N_NODES + 15) / 16 * 64 + 255) / 256;
  const int gemmBlocks = (N_NODES + 63) / 64;

  // ---- layer 1 ----
  al1_kernel<<<(N_NODES * 16 + 255) / 256, 256, 0, stream>>>(x, wa1, al, xbf);
  wagg_kernel<<<waggBlocks, 256, 0, stream>>>(xbf, al, row_off, csr_src, aggx);
  outgemm_stats_kernel<<<gemmBlocks, 256, 0, stream>>>(aggx, w1pT, b1, xbf, batch, y1p, gs1, gss1);
  norm_relu_al_kernel<<<waggBlocks, 256, 0, stream>>>(y1p, batch, gstart, gs1, gss1, l1w, l1b, wa2, y1b, al);

  // ---- layer 2 ----
  wagg_kernel<<<waggBlocks, 256, 0, stream>>>(y1b, al, row_off, csr_src, aggx);
  outgemm_stats_kernel<<<gemmBlocks, 256, 0, stream>>>(aggx, w2pT, b2, y1b, batch, y2p, gs2, gss2);
  norm_relu_pool_kernel<<<waveBlocks, 256, 0, stream>>>(y2p, batch, gstart, gs2, gss2, l2w, l2b, pooled);

  // ---- head ----
  head_kernel<<<(NG * 32 + 255) / 256, 256, 0, stream>>>(pooled, gstart, Wh, bh, out);
}